// Round 2
// baseline (1667.910 us; speedup 1.0000x reference)
//
#include <hip/hip_runtime.h>
#include <hip/hip_bf16.h>
#include <math.h>

#define NB 2
#define CC 192
#define HH 256
#define WW 256
#define NHD 6
#define DH 32
#define C3 576   // 3*CC

__device__ __forceinline__ void fma4(float4& c, const float4& a, float s) {
    c.x = fmaf(a.x, s, c.x);
    c.y = fmaf(a.y, s, c.y);
    c.z = fmaf(a.z, s, c.z);
    c.w = fmaf(a.w, s, c.w);
}

// ---------------------------------------------------------------------------
// K1: 1x1 conv x[n,192,H,W] -> A[576, BH+4, W]  (band rows h0-2 .. h0+BH+1,
// rows outside image written as zeros == zero padding for the first dw conv)
// ---------------------------------------------------------------------------
__global__ __launch_bounds__(256) void k1_qkv(const float* __restrict__ x,
                                              const float* __restrict__ w1,
                                              float* __restrict__ A,
                                              int n, int h0, int BH) {
    const int tilesPerRow = WW / 64;                 // 4
    const int a = blockIdx.x / tilesPerRow;          // 0 .. BH+3
    const int wbase = (blockIdx.x % tilesPerRow) * 64;
    const int gh = h0 - 2 + a;
    const int t = threadIdx.x;
    const int pq = t & 15;          // 16 float4 positions = 64 floats
    const int sg = t >> 4;          // 0..15
    const int OCPT = C3 / 16;       // 36 oc per subgroup
    const int ocbase = sg * OCPT;

    if (gh < 0 || gh >= HH) {       // zero rows (block-uniform branch)
        float4 z = {0.f, 0.f, 0.f, 0.f};
        for (int j = 0; j < OCPT; ++j) {
            float4* A4 = reinterpret_cast<float4*>(A + ((size_t)(ocbase + j) * (BH + 4) + a) * WW + wbase);
            A4[pq] = z;
        }
        return;
    }

    __shared__ float4 xs[CC][16];   // 48 KB
    {
        const float4* x4 = reinterpret_cast<const float4*>(x + ((size_t)(n * CC) * HH + gh) * WW + wbase);
        const size_t icstride = (size_t)HH * WW / 4;
        #pragma unroll
        for (int rr = 0; rr < 12; ++rr) {
            int flat = rr * 256 + t;        // 0..3071
            int ic = flat >> 4, p = flat & 15;
            xs[ic][p] = x4[(size_t)ic * icstride + p];
        }
    }
    __syncthreads();

    for (int j = 0; j < OCPT; j += 2) {
        const int oc0 = ocbase + j, oc1 = oc0 + 1;
        const float4* wr0 = reinterpret_cast<const float4*>(w1 + (size_t)oc0 * CC);
        const float4* wr1 = reinterpret_cast<const float4*>(w1 + (size_t)oc1 * CC);
        float4 acc0 = {0.f, 0.f, 0.f, 0.f};
        float4 acc1 = {0.f, 0.f, 0.f, 0.f};
        #pragma unroll 4
        for (int icb = 0; icb < CC / 4; ++icb) {
            float4 wa = wr0[icb], wb = wr1[icb];
            float4 x0 = xs[4 * icb + 0][pq];
            float4 x1 = xs[4 * icb + 1][pq];
            float4 x2 = xs[4 * icb + 2][pq];
            float4 x3 = xs[4 * icb + 3][pq];
            fma4(acc0, x0, wa.x); fma4(acc0, x1, wa.y); fma4(acc0, x2, wa.z); fma4(acc0, x3, wa.w);
            fma4(acc1, x0, wb.x); fma4(acc1, x1, wb.y); fma4(acc1, x2, wb.z); fma4(acc1, x3, wb.w);
        }
        float4* A40 = reinterpret_cast<float4*>(A + ((size_t)oc0 * (BH + 4) + a) * WW + wbase);
        float4* A41 = reinterpret_cast<float4*>(A + ((size_t)oc1 * (BH + 4) + a) * WW + wbase);
        A40[pq] = acc0;
        A41[pq] = acc1;
    }
}

// ---------------------------------------------------------------------------
// K2: fused depthwise 3x3 (w2) -> depthwise 3x3 (w3).  A[576,BH+4,W] -> B[576,BH,W]
// CRITICAL: the second conv pads the FIRST CONV'S OUTPUT with zeros, so mid
// must be forced to 0 at global positions outside the image.
// ---------------------------------------------------------------------------
__global__ __launch_bounds__(256) void k2_dwdw(const float* __restrict__ A,
                                               const float* __restrict__ w2,
                                               const float* __restrict__ w3,
                                               float* __restrict__ B,
                                               int h0, int BH) {
    const int tilesW = WW / 32;     // 8
    const int tilesR = BH / 32;
    const int bc = blockIdx.x;
    const int c = bc / (tilesR * tilesW);
    const int rem = bc % (tilesR * tilesW);
    const int r0 = (rem / tilesW) * 32;
    const int w0 = (rem % tilesW) * 32;
    const int t = threadIdx.x;

    __shared__ float in[36][37];
    __shared__ float mid[34][35];

    float w2c[9], w3c[9];
    #pragma unroll
    for (int i = 0; i < 9; ++i) { w2c[i] = w2[c * 9 + i]; w3c[i] = w3[c * 9 + i]; }

    const float* Ac = A + (size_t)c * (BH + 4) * WW;
    for (int e = t; e < 36 * 36; e += 256) {
        int rr = e / 36, cc = e % 36;
        int col = w0 - 2 + cc;
        int arow = r0 + rr;                 // within [0, BH+4)
        in[rr][cc] = (col >= 0 && col < WW) ? Ac[(size_t)arow * WW + col] : 0.f;
    }
    __syncthreads();

    for (int e = t; e < 34 * 34; e += 256) {
        int mr = e / 34, mc = e % 34;
        int grow = h0 + r0 + mr - 1;        // global row of this mid element
        int gcol = w0 + mc - 1;             // global col
        float s = 0.f;
        if (grow >= 0 && grow < HH && gcol >= 0 && gcol < WW) {
            #pragma unroll
            for (int i = 0; i < 3; ++i)
                #pragma unroll
                for (int j = 0; j < 3; ++j)
                    s = fmaf(in[mr + i][mc + j], w2c[i * 3 + j], s);
        }
        mid[mr][mc] = s;
    }
    __syncthreads();

    for (int e = t; e < 32 * 32; e += 256) {
        int rr = e >> 5, cc = e & 31;
        float s = 0.f;
        #pragma unroll
        for (int i = 0; i < 3; ++i)
            #pragma unroll
            for (int j = 0; j < 3; ++j)
                s = fmaf(mid[rr + i][cc + j], w3c[i * 3 + j], s);
        B[((size_t)c * BH + r0 + rr) * WW + w0 + cc] = s;
    }
}

// ---------------------------------------------------------------------------
// K3: row-wise attention for one (head, band-row).  B[576,BH,W] -> O[192,BH,W]
// O aliases the A buffer (dead after K2).  256 threads = 256 query positions.
// ---------------------------------------------------------------------------
__global__ __launch_bounds__(256) void k3_attn(const float* __restrict__ B,
                                               const float* __restrict__ factor,
                                               float* __restrict__ O, int BH) {
    const int r = blockIdx.x / NHD;
    const int head = blockIdx.x % NHD;
    const int t = threadIdx.x;
    const size_t plane = (size_t)BH * WW;

    __shared__ float kb[256][36];
    __shared__ float vb[256][36];
    __shared__ float kinv[256];

    // ---- load q rows into kb, pull own row to registers, normalize ----
    const float* qbase = B + (size_t)(head * DH) * plane + (size_t)r * WW;
    #pragma unroll
    for (int d = 0; d < DH; ++d) kb[t][d] = qbase[(size_t)d * plane + t];
    __syncthreads();

    float4 q[8];
    {
        const float4* myrow = reinterpret_cast<const float4*>(&kb[t][0]);
        float ss = 0.f;
        #pragma unroll
        for (int i = 0; i < 8; ++i) {
            q[i] = myrow[i];
            ss = fmaf(q[i].x, q[i].x, ss);
            ss = fmaf(q[i].y, q[i].y, ss);
            ss = fmaf(q[i].z, q[i].z, ss);
            ss = fmaf(q[i].w, q[i].w, ss);
        }
        float inv = factor[0] / fmaxf(sqrtf(ss), 1e-12f);
        #pragma unroll
        for (int i = 0; i < 8; ++i) { q[i].x *= inv; q[i].y *= inv; q[i].z *= inv; q[i].w *= inv; }
    }
    __syncthreads();   // done reading q from kb

    // ---- load k, v rows ----
    const float* kbase = B + (size_t)(CC + head * DH) * plane + (size_t)r * WW;
    const float* vbase = B + (size_t)(2 * CC + head * DH) * plane + (size_t)r * WW;
    #pragma unroll
    for (int d = 0; d < DH; ++d) {
        kb[t][d] = kbase[(size_t)d * plane + t];
        vb[t][d] = vbase[(size_t)d * plane + t];
    }
    __syncthreads();

    {
        const float4* myrow = reinterpret_cast<const float4*>(&kb[t][0]);
        float ss = 0.f;
        #pragma unroll
        for (int i = 0; i < 8; ++i) {
            float4 kv = myrow[i];
            ss = fmaf(kv.x, kv.x, ss);
            ss = fmaf(kv.y, kv.y, ss);
            ss = fmaf(kv.z, kv.z, ss);
            ss = fmaf(kv.w, kv.w, ss);
        }
        kinv[t] = 1.f / fmaxf(sqrtf(ss), 1e-12f);
    }
    __syncthreads();

    // ---- online softmax over kw in chunks of 8 ----
    float4 acc[8];
    #pragma unroll
    for (int i = 0; i < 8; ++i) acc[i] = make_float4(0.f, 0.f, 0.f, 0.f);
    float m = -3.0e38f, l = 0.f;

    for (int kc = 0; kc < WW; kc += 8) {
        float s[8];
        #pragma unroll
        for (int j = 0; j < 8; ++j) {
            const float4* kr = reinterpret_cast<const float4*>(&kb[kc + j][0]);
            float dot = 0.f;
            #pragma unroll
            for (int i = 0; i < 8; ++i) {
                float4 kv = kr[i];
                dot = fmaf(q[i].x, kv.x, dot);
                dot = fmaf(q[i].y, kv.y, dot);
                dot = fmaf(q[i].z, kv.z, dot);
                dot = fmaf(q[i].w, kv.w, dot);
            }
            s[j] = dot * kinv[kc + j];
        }
        float cm = s[0];
        #pragma unroll
        for (int j = 1; j < 8; ++j) cm = fmaxf(cm, s[j]);
        float mn = fmaxf(m, cm);
        float sc = __expf(m - mn);
        l *= sc;
        #pragma unroll
        for (int i = 0; i < 8; ++i) { acc[i].x *= sc; acc[i].y *= sc; acc[i].z *= sc; acc[i].w *= sc; }
        #pragma unroll
        for (int j = 0; j < 8; ++j) {
            float p = __expf(s[j] - mn);
            l += p;
            const float4* vr = reinterpret_cast<const float4*>(&vb[kc + j][0]);
            #pragma unroll
            for (int i = 0; i < 8; ++i) {
                float4 vv = vr[i];
                acc[i].x = fmaf(p, vv.x, acc[i].x);
                acc[i].y = fmaf(p, vv.y, acc[i].y);
                acc[i].z = fmaf(p, vv.z, acc[i].z);
                acc[i].w = fmaf(p, vv.w, acc[i].w);
            }
        }
        m = mn;
    }

    const float invl = 1.f / l;
    float* obase = O + (size_t)(head * DH) * plane + (size_t)r * WW + t;
    #pragma unroll
    for (int i = 0; i < 8; ++i) {
        obase[(size_t)(4 * i + 0) * plane] = acc[i].x * invl;
        obase[(size_t)(4 * i + 1) * plane] = acc[i].y * invl;
        obase[(size_t)(4 * i + 2) * plane] = acc[i].z * invl;
        obase[(size_t)(4 * i + 3) * plane] = acc[i].w * invl;
    }
}

// ---------------------------------------------------------------------------
// K4: final 1x1 conv  O[192,BH,W] -> out[n,192,h0..h0+BH,W]
// ---------------------------------------------------------------------------
__global__ __launch_bounds__(256) void k4_proj(const float* __restrict__ O,
                                               const float* __restrict__ wf,
                                               float* __restrict__ out,
                                               int n, int h0, int BH) {
    const int tilesPerRow = WW / 64;                 // 4
    const int rr = blockIdx.x / tilesPerRow;         // 0..BH-1
    const int wbase = (blockIdx.x % tilesPerRow) * 64;
    const int t = threadIdx.x;
    const int pq = t & 15;
    const int sg = t >> 4;
    const int OCPT = CC / 16;        // 12
    const int ocbase = sg * OCPT;
    const size_t plane4 = (size_t)BH * WW / 4;

    __shared__ float4 xs[CC][16];    // 48 KB
    {
        const float4* O4 = reinterpret_cast<const float4*>(O + (size_t)rr * WW + wbase);
        #pragma unroll
        for (int k = 0; k < 12; ++k) {
            int flat = k * 256 + t;
            int ic = flat >> 4, p = flat & 15;
            xs[ic][p] = O4[(size_t)ic * plane4 + p];
        }
    }
    __syncthreads();

    for (int j = 0; j < OCPT; j += 2) {
        const int oc0 = ocbase + j, oc1 = oc0 + 1;
        const float4* wr0 = reinterpret_cast<const float4*>(wf + (size_t)oc0 * CC);
        const float4* wr1 = reinterpret_cast<const float4*>(wf + (size_t)oc1 * CC);
        float4 acc0 = {0.f, 0.f, 0.f, 0.f};
        float4 acc1 = {0.f, 0.f, 0.f, 0.f};
        #pragma unroll 4
        for (int icb = 0; icb < CC / 4; ++icb) {
            float4 wa = wr0[icb], wb = wr1[icb];
            float4 x0 = xs[4 * icb + 0][pq];
            float4 x1 = xs[4 * icb + 1][pq];
            float4 x2 = xs[4 * icb + 2][pq];
            float4 x3 = xs[4 * icb + 3][pq];
            fma4(acc0, x0, wa.x); fma4(acc0, x1, wa.y); fma4(acc0, x2, wa.z); fma4(acc0, x3, wa.w);
            fma4(acc1, x0, wb.x); fma4(acc1, x1, wb.y); fma4(acc1, x2, wb.z); fma4(acc1, x3, wb.w);
        }
        float4* o40 = reinterpret_cast<float4*>(out + (((size_t)(n * CC + oc0)) * HH + (h0 + rr)) * WW + wbase);
        float4* o41 = reinterpret_cast<float4*>(out + (((size_t)(n * CC + oc1)) * HH + (h0 + rr)) * WW + wbase);
        o40[pq] = acc0;
        o41[pq] = acc1;
    }
}

extern "C" void kernel_launch(void* const* d_in, const int* in_sizes, int n_in,
                              void* d_out, int out_size, void* d_ws, size_t ws_size,
                              hipStream_t stream) {
    const float* x      = (const float*)d_in[0];
    const float* w1     = (const float*)d_in[1];
    const float* w2     = (const float*)d_in[2];
    const float* w3     = (const float*)d_in[3];
    const float* factor = (const float*)d_in[4];
    const float* wf     = (const float*)d_in[5];
    float* out = (float*)d_out;

    // pick band height so that A (qkv1 + halo) and B (qkv3) fit in workspace
    int BH = 128;
    while (BH > 32) {
        size_t need = ((size_t)C3 * (BH + 4) * WW + (size_t)C3 * BH * WW) * sizeof(float);
        if (need <= ws_size) break;
        BH >>= 1;
    }

    float* A = (float*)d_ws;                       // [576][BH+4][W]; later reused as O [192][BH][W]
    float* B = A + (size_t)C3 * (BH + 4) * WW;     // [576][BH][W]

    for (int n = 0; n < NB; ++n) {
        for (int h0 = 0; h0 < HH; h0 += BH) {
            k1_qkv<<<dim3((BH + 4) * (WW / 64)), dim3(256), 0, stream>>>(x, w1, A, n, h0, BH);
            k2_dwdw<<<dim3(C3 * (BH / 32) * (WW / 32)), dim3(256), 0, stream>>>(A, w2, w3, B, h0, BH);
            k3_attn<<<dim3(NHD * BH), dim3(256), 0, stream>>>(B, factor, A, BH);
            k4_proj<<<dim3(BH * (WW / 64)), dim3(256), 0, stream>>>(A, wf, out, n, h0, BH);
        }
    }
}

// Round 3
// 1360.016 us; speedup vs baseline: 1.2264x; 1.2264x over previous
//
#include <hip/hip_runtime.h>
#include <hip/hip_bf16.h>
#include <math.h>

#define NB 2
#define CC 192
#define HH 256
#define WW 256
#define NHD 6
#define DH 32
#define C3 576   // 3*CC

typedef __attribute__((ext_vector_type(8))) short bf16x8;
typedef __attribute__((ext_vector_type(4))) float f32x4;

__device__ __forceinline__ void fma4(float4& c, const float4& a, float s) {
    c.x = fmaf(a.x, s, c.x);
    c.y = fmaf(a.y, s, c.y);
    c.z = fmaf(a.z, s, c.z);
    c.w = fmaf(a.w, s, c.w);
}

__device__ __forceinline__ ushort f2b(float v) {
    __hip_bfloat16 b = __float2bfloat16(v);
    return *reinterpret_cast<ushort*>(&b);
}
__device__ __forceinline__ float b2f(ushort u) {
    __hip_bfloat16 b;
    *reinterpret_cast<ushort*>(&b) = u;
    return __bfloat162float(b);
}

__device__ __forceinline__ void gl_lds16(const void* g, void* l) {
    __builtin_amdgcn_global_load_lds((const __attribute__((address_space(1))) void*)g,
                                     (__attribute__((address_space(3))) void*)l, 16, 0, 0);
}

// ---------------------------------------------------------------------------
// prep_w: split w1[576x192] and wf[192x192] fp32 -> bf16 hi/lo planes.
// Whi/Wlo layout: [768][192] (w1 rows then wf rows), k-contiguous.
// ---------------------------------------------------------------------------
__global__ __launch_bounds__(256) void prep_w(const float* __restrict__ w1,
                                              const float* __restrict__ wf,
                                              ushort* __restrict__ Whi,
                                              ushort* __restrict__ Wlo) {
    int i = blockIdx.x * 256 + threadIdx.x;       // < 147456
    float v = (i < C3 * CC) ? w1[i] : wf[i - C3 * CC];
    ushort h = f2b(v);
    Whi[i] = h;
    Wlo[i] = f2b(v - b2f(h));
}

// ---------------------------------------------------------------------------
// prep_xt: transpose+split band of x -> Xt[p][k] bf16 hi/lo, p = a*256+w,
// a = 0..BH+3 (global row gh = h0-2+a; out-of-range rows -> zeros).
// One block per 64 positions.
// ---------------------------------------------------------------------------
__global__ __launch_bounds__(256) void prep_xt(const float* __restrict__ x,
                                               ushort* __restrict__ Xhi,
                                               ushort* __restrict__ Xlo,
                                               int n, int h0, int BH) {
    const int p0 = blockIdx.x * 64;
    const int gh = h0 - 2 + (p0 >> 8);
    const int wcol = p0 & 255;
    const int t = threadIdx.x;

    if (gh < 0 || gh >= HH) {
        uint* H = (uint*)(Xhi + (size_t)p0 * CC);
        uint* L = (uint*)(Xlo + (size_t)p0 * CC);
        for (int e = t; e < 64 * CC / 2; e += 256) { H[e] = 0u; L[e] = 0u; }
        return;
    }

    __shared__ float xs[CC][65];
    const float* xb = x + ((size_t)n * CC) * (HH * WW) + (size_t)gh * WW + wcol;
    for (int e = t; e < CC * 16; e += 256) {
        int ic = e >> 4, j = e & 15;
        float4 v = *(const float4*)(xb + (size_t)ic * (HH * WW) + j * 4);
        xs[ic][j * 4 + 0] = v.x;
        xs[ic][j * 4 + 1] = v.y;
        xs[ic][j * 4 + 2] = v.z;
        xs[ic][j * 4 + 3] = v.w;
    }
    __syncthreads();

    const int r = t >> 2;            // local position 0..63
    const int k0 = (t & 3) * 48;     // k-chunk
    size_t orow = ((size_t)p0 + r) * CC + k0;
    uint* H = (uint*)(Xhi + orow);
    uint* L = (uint*)(Xlo + orow);
    #pragma unroll
    for (int j = 0; j < 48; j += 2) {
        float va = xs[k0 + j][r], vb = xs[k0 + j + 1][r];
        ushort ha = f2b(va), hb = f2b(vb);
        ushort la = f2b(va - b2f(ha)), lb = f2b(vb - b2f(hb));
        H[j >> 1] = (uint)ha | ((uint)hb << 16);
        L[j >> 1] = (uint)la | ((uint)lb << 16);
    }
}

// ---------------------------------------------------------------------------
// gemm_split: C[M][N] = W[M][192] * X[192][N], split-bf16 (hh + hl + lh).
// W planes: [M][192] bf16, X planes: Xt[N][192] bf16 (k-contiguous rows).
// Block: 256 thr = 4 waves (2x2), tile 64(m) x 128(n), BK=64, 3 K-steps.
// LDS tiles [rows][64] with XOR slot swizzle (slot ^= row&7) applied via
// inverse-swizzled global source (global_load_lds has linear LDS dest).
// ---------------------------------------------------------------------------
__global__ __launch_bounds__(256) void gemm_split(const ushort* __restrict__ Whi,
                                                  const ushort* __restrict__ Wlo,
                                                  const ushort* __restrict__ Xhi,
                                                  const ushort* __restrict__ Xlo,
                                                  float* __restrict__ C, int ldc) {
    __shared__ ushort lA[2][64][64];    // [plane][m][k]  16 KB
    __shared__ ushort lB[2][128][64];   // [plane][p][k]  32 KB

    const int mtile = blockIdx.y * 64;
    const int ptile = blockIdx.x * 128;
    const int t = threadIdx.x, wv = t >> 6, ln = t & 63;
    const int wm = wv >> 1, wn = wv & 1;

    f32x4 zero = {0.f, 0.f, 0.f, 0.f};
    f32x4 acc[2][4];
    #pragma unroll
    for (int fm = 0; fm < 2; ++fm)
        #pragma unroll
        for (int fn = 0; fn < 4; ++fn) acc[fm][fn] = zero;

    const int r8 = ln >> 3, s = ln & 7;

    for (int kk = 0; kk < 3; ++kk) {
        const int k0 = kk * 64;
        // ---- stage: 48 x 1KB wave-chunks, 12 per wave ----
        #pragma unroll
        for (int ci = 0; ci < 12; ++ci) {
            const int c = wv * 12 + ci;
            const ushort* g;
            void* l;
            if (c < 16) {               // A (weights): 2 planes x 8 chunks
                const int pl = c >> 3, ch = c & 7;
                const int r = ch * 8 + r8;
                g = (pl ? Wlo : Whi) + (size_t)(mtile + r) * CC + k0 + ((s ^ (r & 7)) << 3);
                l = (void*)&lA[pl][ch * 8][0];
            } else {                    // B (activations): 2 planes x 16 chunks
                const int c2 = c - 16;
                const int pl = c2 >> 4, ch = c2 & 15;
                const int r = ch * 8 + r8;
                g = (pl ? Xlo : Xhi) + (size_t)(ptile + r) * CC + k0 + ((s ^ (r & 7)) << 3);
                l = (void*)&lB[pl][ch * 8][0];
            }
            gl_lds16(g, l);
        }
        __syncthreads();

        // ---- compute: 2 k-substeps x 3 split products x 2m x 4n MFMA ----
        #pragma unroll
        for (int ks = 0; ks < 2; ++ks) {
            bf16x8 ah[2], al[2], bh[4], bl[4];
            #pragma unroll
            for (int fm = 0; fm < 2; ++fm) {
                const int r = wm * 32 + fm * 16 + (ln & 15);
                const int col = (((ks * 4 + (ln >> 4)) ^ (r & 7)) << 3);
                ah[fm] = *(const bf16x8*)&lA[0][r][col];
                al[fm] = *(const bf16x8*)&lA[1][r][col];
            }
            #pragma unroll
            for (int fn = 0; fn < 4; ++fn) {
                const int r = wn * 64 + fn * 16 + (ln & 15);
                const int col = (((ks * 4 + (ln >> 4)) ^ (r & 7)) << 3);
                bh[fn] = *(const bf16x8*)&lB[0][r][col];
                bl[fn] = *(const bf16x8*)&lB[1][r][col];
            }
            #pragma unroll
            for (int fm = 0; fm < 2; ++fm)
                #pragma unroll
                for (int fn = 0; fn < 4; ++fn) {
                    acc[fm][fn] = __builtin_amdgcn_mfma_f32_16x16x32_bf16(ah[fm], bh[fn], acc[fm][fn], 0, 0, 0);
                    acc[fm][fn] = __builtin_amdgcn_mfma_f32_16x16x32_bf16(ah[fm], bl[fn], acc[fm][fn], 0, 0, 0);
                    acc[fm][fn] = __builtin_amdgcn_mfma_f32_16x16x32_bf16(al[fm], bh[fn], acc[fm][fn], 0, 0, 0);
                }
        }
        __syncthreads();
    }

    // ---- epilogue: D row=(ln>>4)*4+r (m), col=ln&15 (n) ----
    #pragma unroll
    for (int fm = 0; fm < 2; ++fm)
        #pragma unroll
        for (int fn = 0; fn < 4; ++fn)
            #pragma unroll
            for (int r = 0; r < 4; ++r) {
                const int m = mtile + wm * 32 + fm * 16 + (ln >> 4) * 4 + r;
                const int p = ptile + wn * 64 + fn * 16 + (ln & 15);
                C[(size_t)m * ldc + p] = acc[fm][fn][r];
            }
}

// ---------------------------------------------------------------------------
// K2: fused depthwise 3x3 (w2) -> depthwise 3x3 (w3).  A[576,BH+4,W] -> B[576,BH,W]
// mid must be zero at global positions outside the image (second conv pads the
// first conv's OUTPUT).
// ---------------------------------------------------------------------------
__global__ __launch_bounds__(256) void k2_dwdw(const float* __restrict__ A,
                                               const float* __restrict__ w2,
                                               const float* __restrict__ w3,
                                               float* __restrict__ B,
                                               int h0, int BH) {
    const int tilesW = WW / 32;     // 8
    const int tilesR = BH / 32;
    const int bc = blockIdx.x;
    const int c = bc / (tilesR * tilesW);
    const int rem = bc % (tilesR * tilesW);
    const int r0 = (rem / tilesW) * 32;
    const int w0 = (rem % tilesW) * 32;
    const int t = threadIdx.x;

    __shared__ float in[36][37];
    __shared__ float mid[34][35];

    float w2c[9], w3c[9];
    #pragma unroll
    for (int i = 0; i < 9; ++i) { w2c[i] = w2[c * 9 + i]; w3c[i] = w3[c * 9 + i]; }

    const float* Ac = A + (size_t)c * (BH + 4) * WW;
    for (int e = t; e < 36 * 36; e += 256) {
        int rr = e / 36, cc = e % 36;
        int col = w0 - 2 + cc;
        int arow = r0 + rr;
        in[rr][cc] = (col >= 0 && col < WW) ? Ac[(size_t)arow * WW + col] : 0.f;
    }
    __syncthreads();

    for (int e = t; e < 34 * 34; e += 256) {
        int mr = e / 34, mc = e % 34;
        int grow = h0 + r0 + mr - 1;
        int gcol = w0 + mc - 1;
        float sv = 0.f;
        if (grow >= 0 && grow < HH && gcol >= 0 && gcol < WW) {
            #pragma unroll
            for (int i = 0; i < 3; ++i)
                #pragma unroll
                for (int j = 0; j < 3; ++j)
                    sv = fmaf(in[mr + i][mc + j], w2c[i * 3 + j], sv);
        }
        mid[mr][mc] = sv;
    }
    __syncthreads();

    for (int e = t; e < 32 * 32; e += 256) {
        int rr = e >> 5, cc = e & 31;
        float sv = 0.f;
        #pragma unroll
        for (int i = 0; i < 3; ++i)
            #pragma unroll
            for (int j = 0; j < 3; ++j)
                sv = fmaf(mid[rr + i][cc + j], w3c[i * 3 + j], sv);
        B[((size_t)c * BH + r0 + rr) * WW + w0 + cc] = sv;
    }
}

// ---------------------------------------------------------------------------
// K3: row-wise attention.  B[576,BH,W] -> Ot[p][c] bf16 hi/lo (split +
// transposed, ready to be gemm_split's B-operand for the final 1x1 conv).
// ---------------------------------------------------------------------------
__global__ __launch_bounds__(256) void k3_attn(const float* __restrict__ B,
                                               const float* __restrict__ factor,
                                               ushort* __restrict__ Ohi,
                                               ushort* __restrict__ Olo, int BH) {
    const int r = blockIdx.x / NHD;
    const int head = blockIdx.x % NHD;
    const int t = threadIdx.x;
    const size_t plane = (size_t)BH * WW;

    __shared__ float kb[256][36];
    __shared__ float vb[256][36];
    __shared__ float kinv[256];

    // ---- q ----
    const float* qbase = B + (size_t)(head * DH) * plane + (size_t)r * WW;
    #pragma unroll
    for (int d = 0; d < DH; ++d) kb[t][d] = qbase[(size_t)d * plane + t];
    __syncthreads();

    float4 q[8];
    {
        const float4* myrow = reinterpret_cast<const float4*>(&kb[t][0]);
        float ss = 0.f;
        #pragma unroll
        for (int i = 0; i < 8; ++i) {
            q[i] = myrow[i];
            ss = fmaf(q[i].x, q[i].x, ss);
            ss = fmaf(q[i].y, q[i].y, ss);
            ss = fmaf(q[i].z, q[i].z, ss);
            ss = fmaf(q[i].w, q[i].w, ss);
        }
        float inv = factor[0] / fmaxf(sqrtf(ss), 1e-12f);
        #pragma unroll
        for (int i = 0; i < 8; ++i) { q[i].x *= inv; q[i].y *= inv; q[i].z *= inv; q[i].w *= inv; }
    }
    __syncthreads();

    // ---- k, v ----
    const float* kbase = B + (size_t)(CC + head * DH) * plane + (size_t)r * WW;
    const float* vbase = B + (size_t)(2 * CC + head * DH) * plane + (size_t)r * WW;
    #pragma unroll
    for (int d = 0; d < DH; ++d) {
        kb[t][d] = kbase[(size_t)d * plane + t];
        vb[t][d] = vbase[(size_t)d * plane + t];
    }
    __syncthreads();

    {
        const float4* myrow = reinterpret_cast<const float4*>(&kb[t][0]);
        float ss = 0.f;
        #pragma unroll
        for (int i = 0; i < 8; ++i) {
            float4 kv = myrow[i];
            ss = fmaf(kv.x, kv.x, ss);
            ss = fmaf(kv.y, kv.y, ss);
            ss = fmaf(kv.z, kv.z, ss);
            ss = fmaf(kv.w, kv.w, ss);
        }
        kinv[t] = 1.f / fmaxf(sqrtf(ss), 1e-12f);
    }
    __syncthreads();

    // ---- online softmax ----
    float4 acc[8];
    #pragma unroll
    for (int i = 0; i < 8; ++i) acc[i] = make_float4(0.f, 0.f, 0.f, 0.f);
    float m = -3.0e38f, l = 0.f;

    for (int kc = 0; kc < WW; kc += 8) {
        float s[8];
        #pragma unroll
        for (int j = 0; j < 8; ++j) {
            const float4* kr = reinterpret_cast<const float4*>(&kb[kc + j][0]);
            float dot = 0.f;
            #pragma unroll
            for (int i = 0; i < 8; ++i) {
                float4 kv = kr[i];
                dot = fmaf(q[i].x, kv.x, dot);
                dot = fmaf(q[i].y, kv.y, dot);
                dot = fmaf(q[i].z, kv.z, dot);
                dot = fmaf(q[i].w, kv.w, dot);
            }
            s[j] = dot * kinv[kc + j];
        }
        float cm = s[0];
        #pragma unroll
        for (int j = 1; j < 8; ++j) cm = fmaxf(cm, s[j]);
        float mn = fmaxf(m, cm);
        float sc = __expf(m - mn);
        l *= sc;
        #pragma unroll
        for (int i = 0; i < 8; ++i) { acc[i].x *= sc; acc[i].y *= sc; acc[i].z *= sc; acc[i].w *= sc; }
        #pragma unroll
        for (int j = 0; j < 8; ++j) {
            float p = __expf(s[j] - mn);
            l += p;
            const float4* vr = reinterpret_cast<const float4*>(&vb[kc + j][0]);
            #pragma unroll
            for (int i = 0; i < 8; ++i) {
                float4 vv = vr[i];
                acc[i].x = fmaf(p, vv.x, acc[i].x);
                acc[i].y = fmaf(p, vv.y, acc[i].y);
                acc[i].z = fmaf(p, vv.z, acc[i].z);
                acc[i].w = fmaf(p, vv.w, acc[i].w);
            }
        }
        m = mn;
    }

    // ---- write split+transposed: Ot[p][head*32 + d], p = r*256 + t ----
    const float invl = 1.f / l;
    const size_t orow = ((size_t)r * WW + t) * CC + head * DH;
    uint2* H = (uint2*)(Ohi + orow);
    uint2* L = (uint2*)(Olo + orow);
    #pragma unroll
    for (int i = 0; i < 8; ++i) {
        float v0 = acc[i].x * invl, v1 = acc[i].y * invl;
        float v2 = acc[i].z * invl, v3 = acc[i].w * invl;
        ushort h0b = f2b(v0), h1b = f2b(v1), h2b = f2b(v2), h3b = f2b(v3);
        ushort l0b = f2b(v0 - b2f(h0b)), l1b = f2b(v1 - b2f(h1b));
        ushort l2b = f2b(v2 - b2f(h2b)), l3b = f2b(v3 - b2f(h3b));
        H[i] = make_uint2((uint)h0b | ((uint)h1b << 16), (uint)h2b | ((uint)h3b << 16));
        L[i] = make_uint2((uint)l0b | ((uint)l1b << 16), (uint)l2b | ((uint)l3b << 16));
    }
}

extern "C" void kernel_launch(void* const* d_in, const int* in_sizes, int n_in,
                              void* d_out, int out_size, void* d_ws, size_t ws_size,
                              hipStream_t stream) {
    const float* x      = (const float*)d_in[0];
    const float* w1     = (const float*)d_in[1];
    const float* w2     = (const float*)d_in[2];
    const float* w3     = (const float*)d_in[3];
    const float* factor = (const float*)d_in[4];
    const float* wf     = (const float*)d_in[5];
    float* out = (float*)d_out;

    const size_t SW = (size_t)(C3 + CC) * CC * 2 * sizeof(ushort);   // w splits (hi+lo)
    int BH = 128;
    while (BH > 32) {
        size_t SA = (size_t)C3 * (BH + 4) * WW * 4;
        size_t SB = (size_t)C3 * BH * WW * 4;
        if (SA + SB + SW <= ws_size) break;
        BH >>= 1;
    }
    const size_t SA = (size_t)C3 * (BH + 4) * WW * 4;
    const size_t SB = (size_t)C3 * BH * WW * 4;

    float*  A   = (float*)d_ws;                            // qkv1 region; later Ot hi/lo
    float*  Bq  = (float*)((char*)d_ws + SA);              // qkv3 region; earlier Xt hi/lo
    ushort* Wsp = (ushort*)((char*)d_ws + SA + SB);        // weight splits
    ushort* Whi = Wsp;                                     // [768][192]
    ushort* Wlo = Wsp + (size_t)(C3 + CC) * CC;

    ushort* Xhi = (ushort*)Bq;                             // [(BH+4)*256][192]
    ushort* Xlo = Xhi + (size_t)(BH + 4) * WW * CC;
    ushort* Ohi = (ushort*)A;                              // [BH*256][192]
    ushort* Olo = Ohi + (size_t)BH * WW * CC;

    prep_w<<<dim3((C3 + CC) * CC / 256), dim3(256), 0, stream>>>(w1, wf, Whi, Wlo);

    for (int n = 0; n < NB; ++n) {
        for (int h0 = 0; h0 < HH; h0 += BH) {
            prep_xt<<<dim3((BH + 4) * (WW / 64)), dim3(256), 0, stream>>>(x, Xhi, Xlo, n, h0, BH);
            gemm_split<<<dim3((BH + 4) * WW / 128, C3 / 64), dim3(256), 0, stream>>>(
                Whi, Wlo, Xhi, Xlo, A, (BH + 4) * WW);
            k2_dwdw<<<dim3(C3 * (BH / 32) * (WW / 32)), dim3(256), 0, stream>>>(A, w2, w3, Bq, h0, BH);
            k3_attn<<<dim3(NHD * BH), dim3(256), 0, stream>>>(Bq, factor, Ohi, Olo, BH);
            gemm_split<<<dim3(BH * WW / 128, CC / 64), dim3(256), 0, stream>>>(
                Whi + (size_t)C3 * CC, Wlo + (size_t)C3 * CC, Ohi, Olo,
                out + ((size_t)n * CC) * HH * WW + (size_t)h0 * WW, HH * WW);
        }
    }
}

// Round 4
// 744.924 us; speedup vs baseline: 2.2390x; 1.8257x over previous
//
#include <hip/hip_runtime.h>
#include <hip/hip_bf16.h>
#include <math.h>

#define NB 2
#define CC 192
#define HH 256
#define WW 256
#define NHD 6
#define DH 32
#define C3 576   // 3*CC

typedef __attribute__((ext_vector_type(8))) short bf16x8;
typedef __attribute__((ext_vector_type(4))) float f32x4;

__device__ __forceinline__ void fma4(float4& c, const float4& a, float s) {
    c.x = fmaf(a.x, s, c.x);
    c.y = fmaf(a.y, s, c.y);
    c.z = fmaf(a.z, s, c.z);
    c.w = fmaf(a.w, s, c.w);
}

__device__ __forceinline__ ushort f2b(float v) {
    __hip_bfloat16 b = __float2bfloat16(v);
    return *reinterpret_cast<ushort*>(&b);
}
__device__ __forceinline__ float b2f(ushort u) {
    __hip_bfloat16 b;
    *reinterpret_cast<ushort*>(&b) = u;
    return __bfloat162float(b);
}

__device__ __forceinline__ void gl_lds16(const void* g, void* l) {
    __builtin_amdgcn_global_load_lds((const __attribute__((address_space(1))) void*)g,
                                     (__attribute__((address_space(3))) void*)l, 16, 0, 0);
}

// ---------------------------------------------------------------------------
// prep_w: split w1[576x192] and wf[192x192] fp32 -> bf16 hi/lo planes.
// ---------------------------------------------------------------------------
__global__ __launch_bounds__(256) void prep_w(const float* __restrict__ w1,
                                              const float* __restrict__ wf,
                                              ushort* __restrict__ Whi,
                                              ushort* __restrict__ Wlo) {
    int i = blockIdx.x * 256 + threadIdx.x;       // < 147456
    float v = (i < C3 * CC) ? w1[i] : wf[i - C3 * CC];
    ushort h = f2b(v);
    Whi[i] = h;
    Wlo[i] = f2b(v - b2f(h));
}

// ---------------------------------------------------------------------------
// prep_xt: transpose+split band of x -> Xt[p][k] bf16 hi/lo, p = a*256+w.
// ---------------------------------------------------------------------------
__global__ __launch_bounds__(256) void prep_xt(const float* __restrict__ x,
                                               ushort* __restrict__ Xhi,
                                               ushort* __restrict__ Xlo,
                                               int n, int h0, int BH) {
    const int p0 = blockIdx.x * 64;
    const int gh = h0 - 2 + (p0 >> 8);
    const int wcol = p0 & 255;
    const int t = threadIdx.x;

    if (gh < 0 || gh >= HH) {
        uint* H = (uint*)(Xhi + (size_t)p0 * CC);
        uint* L = (uint*)(Xlo + (size_t)p0 * CC);
        for (int e = t; e < 64 * CC / 2; e += 256) { H[e] = 0u; L[e] = 0u; }
        return;
    }

    __shared__ float xs[CC][65];
    const float* xb = x + ((size_t)n * CC) * (HH * WW) + (size_t)gh * WW + wcol;
    for (int e = t; e < CC * 16; e += 256) {
        int ic = e >> 4, j = e & 15;
        float4 v = *(const float4*)(xb + (size_t)ic * (HH * WW) + j * 4);
        xs[ic][j * 4 + 0] = v.x;
        xs[ic][j * 4 + 1] = v.y;
        xs[ic][j * 4 + 2] = v.z;
        xs[ic][j * 4 + 3] = v.w;
    }
    __syncthreads();

    const int r = t >> 2;            // local position 0..63
    const int k0 = (t & 3) * 48;     // k-chunk
    size_t orow = ((size_t)p0 + r) * CC + k0;
    uint* H = (uint*)(Xhi + orow);
    uint* L = (uint*)(Xlo + orow);
    #pragma unroll
    for (int j = 0; j < 48; j += 2) {
        float va = xs[k0 + j][r], vb = xs[k0 + j + 1][r];
        ushort ha = f2b(va), hb = f2b(vb);
        ushort la = f2b(va - b2f(ha)), lb = f2b(vb - b2f(hb));
        H[j >> 1] = (uint)ha | ((uint)hb << 16);
        L[j >> 1] = (uint)la | ((uint)lb << 16);
    }
}

// ---------------------------------------------------------------------------
// gemm_split: C[M][N] = W[M][192] * X[192][N], split-bf16 (hh + hl + lh).
// ---------------------------------------------------------------------------
__global__ __launch_bounds__(256) void gemm_split(const ushort* __restrict__ Whi,
                                                  const ushort* __restrict__ Wlo,
                                                  const ushort* __restrict__ Xhi,
                                                  const ushort* __restrict__ Xlo,
                                                  float* __restrict__ C, int ldc) {
    __shared__ ushort lA[2][64][64];    // [plane][m][k]  16 KB
    __shared__ ushort lB[2][128][64];   // [plane][p][k]  32 KB

    const int mtile = blockIdx.y * 64;
    const int ptile = blockIdx.x * 128;
    const int t = threadIdx.x, wv = t >> 6, ln = t & 63;
    const int wm = wv >> 1, wn = wv & 1;

    f32x4 zero = {0.f, 0.f, 0.f, 0.f};
    f32x4 acc[2][4];
    #pragma unroll
    for (int fm = 0; fm < 2; ++fm)
        #pragma unroll
        for (int fn = 0; fn < 4; ++fn) acc[fm][fn] = zero;

    const int r8 = ln >> 3, s = ln & 7;

    for (int kk = 0; kk < 3; ++kk) {
        const int k0 = kk * 64;
        #pragma unroll
        for (int ci = 0; ci < 12; ++ci) {
            const int c = wv * 12 + ci;
            const ushort* g;
            void* l;
            if (c < 16) {               // A (weights)
                const int pl = c >> 3, ch = c & 7;
                const int r = ch * 8 + r8;
                g = (pl ? Wlo : Whi) + (size_t)(mtile + r) * CC + k0 + ((s ^ (r & 7)) << 3);
                l = (void*)&lA[pl][ch * 8][0];
            } else {                    // B (activations)
                const int c2 = c - 16;
                const int pl = c2 >> 4, ch = c2 & 15;
                const int r = ch * 8 + r8;
                g = (pl ? Xlo : Xhi) + (size_t)(ptile + r) * CC + k0 + ((s ^ (r & 7)) << 3);
                l = (void*)&lB[pl][ch * 8][0];
            }
            gl_lds16(g, l);
        }
        __syncthreads();

        #pragma unroll
        for (int ks = 0; ks < 2; ++ks) {
            bf16x8 ah[2], al[2], bh[4], bl[4];
            #pragma unroll
            for (int fm = 0; fm < 2; ++fm) {
                const int r = wm * 32 + fm * 16 + (ln & 15);
                const int col = (((ks * 4 + (ln >> 4)) ^ (r & 7)) << 3);
                ah[fm] = *(const bf16x8*)&lA[0][r][col];
                al[fm] = *(const bf16x8*)&lA[1][r][col];
            }
            #pragma unroll
            for (int fn = 0; fn < 4; ++fn) {
                const int r = wn * 64 + fn * 16 + (ln & 15);
                const int col = (((ks * 4 + (ln >> 4)) ^ (r & 7)) << 3);
                bh[fn] = *(const bf16x8*)&lB[0][r][col];
                bl[fn] = *(const bf16x8*)&lB[1][r][col];
            }
            #pragma unroll
            for (int fm = 0; fm < 2; ++fm)
                #pragma unroll
                for (int fn = 0; fn < 4; ++fn) {
                    acc[fm][fn] = __builtin_amdgcn_mfma_f32_16x16x32_bf16(ah[fm], bh[fn], acc[fm][fn], 0, 0, 0);
                    acc[fm][fn] = __builtin_amdgcn_mfma_f32_16x16x32_bf16(ah[fm], bl[fn], acc[fm][fn], 0, 0, 0);
                    acc[fm][fn] = __builtin_amdgcn_mfma_f32_16x16x32_bf16(al[fm], bh[fn], acc[fm][fn], 0, 0, 0);
                }
        }
        __syncthreads();
    }

    #pragma unroll
    for (int fm = 0; fm < 2; ++fm)
        #pragma unroll
        for (int fn = 0; fn < 4; ++fn)
            #pragma unroll
            for (int r = 0; r < 4; ++r) {
                const int m = mtile + wm * 32 + fm * 16 + (ln >> 4) * 4 + r;
                const int p = ptile + wn * 64 + fn * 16 + (ln & 15);
                C[(size_t)m * ldc + p] = acc[fm][fn][r];
            }
}

// ---------------------------------------------------------------------------
// K2: fused depthwise 3x3 -> depthwise 3x3.  A[576,BH+4,W] -> B[576,BH,W]
// ---------------------------------------------------------------------------
__global__ __launch_bounds__(256) void k2_dwdw(const float* __restrict__ A,
                                               const float* __restrict__ w2,
                                               const float* __restrict__ w3,
                                               float* __restrict__ B,
                                               int h0, int BH) {
    const int tilesW = WW / 32;     // 8
    const int tilesR = BH / 32;
    const int bc = blockIdx.x;
    const int c = bc / (tilesR * tilesW);
    const int rem = bc % (tilesR * tilesW);
    const int r0 = (rem / tilesW) * 32;
    const int w0 = (rem % tilesW) * 32;
    const int t = threadIdx.x;

    __shared__ float in[36][37];
    __shared__ float mid[34][35];

    float w2c[9], w3c[9];
    #pragma unroll
    for (int i = 0; i < 9; ++i) { w2c[i] = w2[c * 9 + i]; w3c[i] = w3[c * 9 + i]; }

    const float* Ac = A + (size_t)c * (BH + 4) * WW;
    for (int e = t; e < 36 * 36; e += 256) {
        int rr = e / 36, cc = e % 36;
        int col = w0 - 2 + cc;
        int arow = r0 + rr;
        in[rr][cc] = (col >= 0 && col < WW) ? Ac[(size_t)arow * WW + col] : 0.f;
    }
    __syncthreads();

    for (int e = t; e < 34 * 34; e += 256) {
        int mr = e / 34, mc = e % 34;
        int grow = h0 + r0 + mr - 1;
        int gcol = w0 + mc - 1;
        float sv = 0.f;
        if (grow >= 0 && grow < HH && gcol >= 0 && gcol < WW) {
            #pragma unroll
            for (int i = 0; i < 3; ++i)
                #pragma unroll
                for (int j = 0; j < 3; ++j)
                    sv = fmaf(in[mr + i][mc + j], w2c[i * 3 + j], sv);
        }
        mid[mr][mc] = sv;
    }
    __syncthreads();

    for (int e = t; e < 32 * 32; e += 256) {
        int rr = e >> 5, cc = e & 31;
        float sv = 0.f;
        #pragma unroll
        for (int i = 0; i < 3; ++i)
            #pragma unroll
            for (int j = 0; j < 3; ++j)
                sv = fmaf(mid[rr + i][cc + j], w3c[i * 3 + j], sv);
        B[((size_t)c * BH + r0 + rr) * WW + w0 + cc] = sv;
    }
}

// ---------------------------------------------------------------------------
// K3 (MFMA): row-wise attention for one (band-row, head).
// 512 thr = 8 waves, each wave owns 32 queries (2 chunks of 16).
// S^T = mfma(A=K, B=Q): lane&15 = query, 64 S-values per lane -> in-lane
// softmax + shfl_xor(16,32).  PV uses a PERMUTED contraction order so each
// lane's exp'd S^T registers ARE its P^T B-fragment (no cross-lane moves);
// V is staged with matching permuted columns.  All products split-bf16.
// Out is transposed through (dead) LDS and written as split Ohi/Olo [p][c].
// ---------------------------------------------------------------------------
__global__ __launch_bounds__(512, 2) void k3_attn_mfma(const float* __restrict__ Bq,
                                                       const float* __restrict__ factor,
                                                       ushort* __restrict__ Ohi,
                                                       ushort* __restrict__ Olo, int BH) {
    const int r = blockIdx.x / NHD;
    const int head = blockIdx.x % NHD;
    const int t = threadIdx.x;
    const size_t plane = (size_t)BH * WW;

    __shared__ __align__(16) char arena[98304];
    ushort* Ksp = (ushort*)arena;            // [2][256 key][32 d]  slot-swizzled
    ushort* Vt  = (ushort*)(arena + 32768);  // [2][32 d][256 key'] permuted+swizzled
    ushort* Qsp = (ushort*)(arena + 65536);  // [2][256 q][32 d]   slot-swizzled
    uint*   Oar = (uint*)arena;              // [2][256][20] epilogue (aliases Ksp/Vt)

    // ---- stage q (t<256) / k (t>=256): load row, normalize, split, swizzle ----
    {
        const int role = t >> 8;            // 0=q, 1=k
        const int row = t & 255;
        const float* base = Bq + ((size_t)(role * CC + head * DH)) * plane + (size_t)r * WW + row;
        float v[32];
        #pragma unroll
        for (int d = 0; d < 32; ++d) v[d] = base[(size_t)d * plane];
        float ss = 0.f;
        #pragma unroll
        for (int d = 0; d < 32; ++d) ss = fmaf(v[d], v[d], ss);
        float inv = 1.f / fmaxf(sqrtf(ss), 1e-12f);
        if (!role) inv *= factor[0];
        ushort* dst = role ? Ksp : Qsp;
        const int sw = (row >> 1) & 3;
        #pragma unroll
        for (int d = 0; d < 32; d += 2) {
            float v0 = v[d] * inv, v1 = v[d + 1] * inv;
            ushort h0 = f2b(v0), h1 = f2b(v1);
            ushort g0 = f2b(v0 - b2f(h0)), g1 = f2b(v1 - b2f(h1));
            int dd = (d & 7) | ((((d >> 3) ^ sw) & 3) << 3);   // even, slot-swizzled
            *(uint*)&dst[row * 32 + dd] = (uint)h0 | ((uint)h1 << 16);
            *(uint*)&dst[8192 + row * 32 + dd] = (uint)g0 | ((uint)g1 << 16);
        }
    }
    // ---- stage v (t<256): permuted columns key' = 32s|8g|4b|rr ----
    if (t < 256) {
        const int k = t;
        const int kp = (k & 0xE3) | (((k >> 2) & 3) << 3) | (((k >> 4) & 1) << 2);
        const float* base = Bq + ((size_t)(2 * CC + head * DH)) * plane + (size_t)r * WW + k;
        const int slot = kp >> 3, inb = kp & 7;
        #pragma unroll
        for (int d = 0; d < 32; ++d) {
            float val = base[(size_t)d * plane];
            ushort h = f2b(val);
            ushort g = f2b(val - b2f(h));
            int col = ((slot ^ (d & 7)) << 3) | inb;
            Vt[d * 256 + col] = h;
            Vt[8192 + d * 256 + col] = g;
        }
    }
    __syncthreads();

    const int wv = t >> 6, ln = t & 63;
    const int hig = ln >> 4, lo16 = ln & 15;

    f32x4 osave[2][2];
    float invl[2];

    #pragma unroll
    for (int c = 0; c < 2; ++c) {
        const int qrow = wv * 32 + c * 16 + lo16;
        const int qoff = qrow * 32 + ((hig ^ ((qrow >> 1) & 3)) << 3);
        const bf16x8 qh = *(const bf16x8*)&Qsp[qoff];
        const bf16x8 qlo = *(const bf16x8*)&Qsp[8192 + qoff];

        // ---- S^T: 16 key-frags, split products hh+hl+lh ----
        f32x4 s[16];
        #pragma unroll
        for (int f = 0; f < 16; ++f) {
            const int krow = f * 16 + lo16;
            const int koff = krow * 32 + ((hig ^ ((krow >> 1) & 3)) << 3);
            const bf16x8 kh = *(const bf16x8*)&Ksp[koff];
            const bf16x8 klo = *(const bf16x8*)&Ksp[8192 + koff];
            f32x4 a = {0.f, 0.f, 0.f, 0.f};
            a = __builtin_amdgcn_mfma_f32_16x16x32_bf16(kh, qh, a, 0, 0, 0);
            a = __builtin_amdgcn_mfma_f32_16x16x32_bf16(kh, qlo, a, 0, 0, 0);
            a = __builtin_amdgcn_mfma_f32_16x16x32_bf16(klo, qh, a, 0, 0, 0);
            s[f] = a;
        }

        // ---- softmax (lane holds full row for q = lane&15) ----
        float mx = -3.0e38f;
        #pragma unroll
        for (int f = 0; f < 16; ++f)
            mx = fmaxf(mx, fmaxf(fmaxf(s[f][0], s[f][1]), fmaxf(s[f][2], s[f][3])));
        mx = fmaxf(mx, __shfl_xor(mx, 16));
        mx = fmaxf(mx, __shfl_xor(mx, 32));
        float lsum = 0.f;
        #pragma unroll
        for (int f = 0; f < 16; ++f) {
            #pragma unroll
            for (int rr = 0; rr < 4; ++rr) {
                float p = __expf(s[f][rr] - mx);
                s[f][rr] = p;
                lsum += p;
            }
        }
        lsum += __shfl_xor(lsum, 16);
        lsum += __shfl_xor(lsum, 32);
        invl[c] = 1.f / lsum;

        // ---- pack P to split bf16 (local, pairs along regs) ----
        uint phh[16][2], pll[16][2];
        #pragma unroll
        for (int f = 0; f < 16; ++f) {
            ushort h0 = f2b(s[f][0]), h1 = f2b(s[f][1]), h2 = f2b(s[f][2]), h3 = f2b(s[f][3]);
            phh[f][0] = (uint)h0 | ((uint)h1 << 16);
            phh[f][1] = (uint)h2 | ((uint)h3 << 16);
            ushort g0 = f2b(s[f][0] - b2f(h0)), g1 = f2b(s[f][1] - b2f(h1));
            ushort g2 = f2b(s[f][2] - b2f(h2)), g3 = f2b(s[f][3] - b2f(h3));
            pll[f][0] = (uint)g0 | ((uint)g1 << 16);
            pll[f][1] = (uint)g2 | ((uint)g3 << 16);
        }

        // ---- PV over permuted key order: out^T = V^T x P^T ----
        f32x4 o0a = {0,0,0,0}, o0b = {0,0,0,0}, o1a = {0,0,0,0}, o1b = {0,0,0,0};
        #pragma unroll
        for (int st = 0; st < 8; ++st) {
            union { bf16x8 v; uint u[4]; } pbh, pbl;
            pbh.u[0] = phh[2*st][0];   pbh.u[1] = phh[2*st][1];
            pbh.u[2] = phh[2*st+1][0]; pbh.u[3] = phh[2*st+1][1];
            pbl.u[0] = pll[2*st][0];   pbl.u[1] = pll[2*st][1];
            pbl.u[2] = pll[2*st+1][0]; pbl.u[3] = pll[2*st+1][1];
            {
                const int drow = lo16;
                const int voff = drow * 256 + (((4*st + hig) ^ (drow & 7)) << 3);
                const bf16x8 vh = *(const bf16x8*)&Vt[voff];
                const bf16x8 vl = *(const bf16x8*)&Vt[8192 + voff];
                f32x4& o = (st & 1) ? o0b : o0a;
                o = __builtin_amdgcn_mfma_f32_16x16x32_bf16(vh, pbh.v, o, 0, 0, 0);
                o = __builtin_amdgcn_mfma_f32_16x16x32_bf16(vh, pbl.v, o, 0, 0, 0);
                o = __builtin_amdgcn_mfma_f32_16x16x32_bf16(vl, pbh.v, o, 0, 0, 0);
            }
            {
                const int drow = 16 + lo16;
                const int voff = drow * 256 + (((4*st + hig) ^ (drow & 7)) << 3);
                const bf16x8 vh = *(const bf16x8*)&Vt[voff];
                const bf16x8 vl = *(const bf16x8*)&Vt[8192 + voff];
                f32x4& o = (st & 1) ? o1b : o1a;
                o = __builtin_amdgcn_mfma_f32_16x16x32_bf16(vh, pbh.v, o, 0, 0, 0);
                o = __builtin_amdgcn_mfma_f32_16x16x32_bf16(vh, pbl.v, o, 0, 0, 0);
                o = __builtin_amdgcn_mfma_f32_16x16x32_bf16(vl, pbh.v, o, 0, 0, 0);
            }
        }
        #pragma unroll
        for (int rr = 0; rr < 4; ++rr) { o0a[rr] += o0b[rr]; o1a[rr] += o1b[rr]; }
        osave[c][0] = o0a;
        osave[c][1] = o1a;
    }

    __syncthreads();   // all waves done reading Ksp/Vt before Oar overwrite

    // ---- scale + split + transpose through LDS ----
    #pragma unroll
    for (int c = 0; c < 2; ++c) {
        const int qrow = wv * 32 + c * 16 + lo16;
        #pragma unroll
        for (int fm = 0; fm < 2; ++fm) {
            const f32x4 o = osave[c][fm];
            const float s0 = o[0] * invl[c], s1 = o[1] * invl[c];
            const float s2 = o[2] * invl[c], s3 = o[3] * invl[c];
            const ushort h0 = f2b(s0), h1 = f2b(s1), h2 = f2b(s2), h3 = f2b(s3);
            const ushort g0 = f2b(s0 - b2f(h0)), g1 = f2b(s1 - b2f(h1));
            const ushort g2 = f2b(s2 - b2f(h2)), g3 = f2b(s3 - b2f(h3));
            const int dp = 8 * fm + 2 * hig;           // u32 index of d-pair
            Oar[qrow * 20 + dp]            = (uint)h0 | ((uint)h1 << 16);
            Oar[qrow * 20 + dp + 1]        = (uint)h2 | ((uint)h3 << 16);
            Oar[5120 + qrow * 20 + dp]     = (uint)g0 | ((uint)g1 << 16);
            Oar[5120 + qrow * 20 + dp + 1] = (uint)g2 | ((uint)g3 << 16);
        }
    }
    __syncthreads();

    // ---- coalesced 64B-line writes of the split transposed output ----
    if (t < 256) {
        const size_t obase = ((size_t)r * WW + t) * CC + head * DH;   // ushort index
        uint4* dh_ = (uint4*)(Ohi + obase);
        uint4* dl_ = (uint4*)(Olo + obase);
        const uint* srcH = &Oar[t * 20];
        const uint* srcL = &Oar[5120 + t * 20];
        #pragma unroll
        for (int i = 0; i < 4; ++i) {
            dh_[i] = *(const uint4*)&srcH[i * 4];
            dl_[i] = *(const uint4*)&srcL[i * 4];
        }
    }
}

extern "C" void kernel_launch(void* const* d_in, const int* in_sizes, int n_in,
                              void* d_out, int out_size, void* d_ws, size_t ws_size,
                              hipStream_t stream) {
    const float* x      = (const float*)d_in[0];
    const float* w1     = (const float*)d_in[1];
    const float* w2     = (const float*)d_in[2];
    const float* w3     = (const float*)d_in[3];
    const float* factor = (const float*)d_in[4];
    const float* wf     = (const float*)d_in[5];
    float* out = (float*)d_out;

    const size_t SW = (size_t)(C3 + CC) * CC * 2 * sizeof(ushort);   // w splits (hi+lo)
    int BH = 128;
    while (BH > 32) {
        size_t SA = (size_t)C3 * (BH + 4) * WW * 4;
        size_t SB = (size_t)C3 * BH * WW * 4;
        if (SA + SB + SW <= ws_size) break;
        BH >>= 1;
    }
    const size_t SA = (size_t)C3 * (BH + 4) * WW * 4;
    const size_t SB = (size_t)C3 * BH * WW * 4;

    float*  A   = (float*)d_ws;                            // qkv1 region; later Ot hi/lo
    float*  Bq  = (float*)((char*)d_ws + SA);              // qkv3 region; earlier Xt hi/lo
    ushort* Wsp = (ushort*)((char*)d_ws + SA + SB);        // weight splits
    ushort* Whi = Wsp;                                     // [768][192]
    ushort* Wlo = Wsp + (size_t)(C3 + CC) * CC;

    ushort* Xhi = (ushort*)Bq;                             // [(BH+4)*256][192]
    ushort* Xlo = Xhi + (size_t)(BH + 4) * WW * CC;
    ushort* Ohi = (ushort*)A;                              // [BH*256][192]
    ushort* Olo = Ohi + (size_t)BH * WW * CC;

    prep_w<<<dim3((C3 + CC) * CC / 256), dim3(256), 0, stream>>>(w1, wf, Whi, Wlo);

    for (int n = 0; n < NB; ++n) {
        for (int h0 = 0; h0 < HH; h0 += BH) {
            prep_xt<<<dim3((BH + 4) * (WW / 64)), dim3(256), 0, stream>>>(x, Xhi, Xlo, n, h0, BH);
            gemm_split<<<dim3((BH + 4) * WW / 128, C3 / 64), dim3(256), 0, stream>>>(
                Whi, Wlo, Xhi, Xlo, A, (BH + 4) * WW);
            k2_dwdw<<<dim3(C3 * (BH / 32) * (WW / 32)), dim3(256), 0, stream>>>(A, w2, w3, Bq, h0, BH);
            k3_attn_mfma<<<dim3(NHD * BH), dim3(512), 0, stream>>>(Bq, factor, Ohi, Olo, BH);
            gemm_split<<<dim3(BH * WW / 128, CC / 64), dim3(256), 0, stream>>>(
                Whi + (size_t)C3 * CC, Wlo + (size_t)C3 * CC, Ohi, Olo,
                out + ((size_t)n * CC) * HH * WW + (size_t)h0 * WW, HH * WW);
        }
    }
}

// Round 5
// 674.899 us; speedup vs baseline: 2.4713x; 1.1038x over previous
//
#include <hip/hip_runtime.h>
#include <hip/hip_bf16.h>
#include <math.h>

#define NB 2
#define CC 192
#define HH 256
#define WW 256
#define NHD 6
#define DH 32
#define C3 576   // 3*CC

typedef __attribute__((ext_vector_type(8))) short bf16x8;
typedef __attribute__((ext_vector_type(4))) float f32x4;

__device__ __forceinline__ ushort f2b(float v) {
    __hip_bfloat16 b = __float2bfloat16(v);
    return *reinterpret_cast<ushort*>(&b);
}
__device__ __forceinline__ float b2f(ushort u) {
    __hip_bfloat16 b;
    *reinterpret_cast<ushort*>(&b) = u;
    return __bfloat162float(b);
}

__device__ __forceinline__ void gl_lds16(const void* g, void* l) {
    __builtin_amdgcn_global_load_lds((const __attribute__((address_space(1))) void*)g,
                                     (__attribute__((address_space(3))) void*)l, 16, 0, 0);
}

// ---------------------------------------------------------------------------
// prep_w: split w1[576x192] and wf[192x192] fp32 -> bf16 hi/lo planes.
// ---------------------------------------------------------------------------
__global__ __launch_bounds__(256) void prep_w(const float* __restrict__ w1,
                                              const float* __restrict__ wf,
                                              ushort* __restrict__ Whi,
                                              ushort* __restrict__ Wlo) {
    int i = blockIdx.x * 256 + threadIdx.x;       // < 147456
    float v = (i < C3 * CC) ? w1[i] : wf[i - C3 * CC];
    ushort h = f2b(v);
    Whi[i] = h;
    Wlo[i] = f2b(v - b2f(h));
}

// ---------------------------------------------------------------------------
// prep_xt: transpose+split band of x -> Xt[p][k] bf16 hi/lo, p = a*256+w.
// ---------------------------------------------------------------------------
__global__ __launch_bounds__(256) void prep_xt(const float* __restrict__ x,
                                               ushort* __restrict__ Xhi,
                                               ushort* __restrict__ Xlo,
                                               int n, int h0, int BH) {
    const int p0 = blockIdx.x * 64;
    const int gh = h0 - 2 + (p0 >> 8);
    const int wcol = p0 & 255;
    const int t = threadIdx.x;

    if (gh < 0 || gh >= HH) {
        uint* H = (uint*)(Xhi + (size_t)p0 * CC);
        uint* L = (uint*)(Xlo + (size_t)p0 * CC);
        for (int e = t; e < 64 * CC / 2; e += 256) { H[e] = 0u; L[e] = 0u; }
        return;
    }

    __shared__ float xs[CC][65];
    const float* xb = x + ((size_t)n * CC) * (HH * WW) + (size_t)gh * WW + wcol;
    for (int e = t; e < CC * 16; e += 256) {
        int ic = e >> 4, j = e & 15;
        float4 v = *(const float4*)(xb + (size_t)ic * (HH * WW) + j * 4);
        xs[ic][j * 4 + 0] = v.x;
        xs[ic][j * 4 + 1] = v.y;
        xs[ic][j * 4 + 2] = v.z;
        xs[ic][j * 4 + 3] = v.w;
    }
    __syncthreads();

    const int r = t >> 2;            // local position 0..63
    const int k0 = (t & 3) * 48;     // k-chunk
    size_t orow = ((size_t)p0 + r) * CC + k0;
    uint* H = (uint*)(Xhi + orow);
    uint* L = (uint*)(Xlo + orow);
    #pragma unroll
    for (int j = 0; j < 48; j += 2) {
        float va = xs[k0 + j][r], vb = xs[k0 + j + 1][r];
        ushort ha = f2b(va), hb = f2b(vb);
        ushort la = f2b(va - b2f(ha)), lb = f2b(vb - b2f(hb));
        H[j >> 1] = (uint)ha | ((uint)hb << 16);
        L[j >> 1] = (uint)la | ((uint)lb << 16);
    }
}

// ---------------------------------------------------------------------------
// gemm_split: C[M][N] = W[M][192] * B[192][N], split-bf16 (hh + hl + lh).
// B-operand addressing generalized: element (row p, k) lives at
//   Bpl + (k>>5)*SS + p*RS + (k&31)
// K1 (Xt [p][192] contiguous): RS=192, SS=32.
// K4 (O  [head][p][32]):       RS=32,  SS=BH*256*32.
// ---------------------------------------------------------------------------
__global__ __launch_bounds__(256) void gemm_split(const ushort* __restrict__ Whi,
                                                  const ushort* __restrict__ Wlo,
                                                  const ushort* __restrict__ Bhi,
                                                  const ushort* __restrict__ Blo,
                                                  float* __restrict__ C, int ldc,
                                                  int RS, int SS) {
    __shared__ ushort lA[2][64][64];    // [plane][m][k]  16 KB
    __shared__ ushort lB[2][128][64];   // [plane][p][k]  32 KB

    const int mtile = blockIdx.y * 64;
    const int ptile = blockIdx.x * 128;
    const int t = threadIdx.x, wv = t >> 6, ln = t & 63;
    const int wm = wv >> 1, wn = wv & 1;

    f32x4 zero = {0.f, 0.f, 0.f, 0.f};
    f32x4 acc[2][4];
    #pragma unroll
    for (int fm = 0; fm < 2; ++fm)
        #pragma unroll
        for (int fn = 0; fn < 4; ++fn) acc[fm][fn] = zero;

    const int r8 = ln >> 3, s = ln & 7;

    for (int kk = 0; kk < 3; ++kk) {
        const int k0 = kk * 64;
        #pragma unroll
        for (int ci = 0; ci < 12; ++ci) {
            const int c = wv * 12 + ci;
            const ushort* g;
            void* l;
            if (c < 16) {               // A (weights)
                const int pl = c >> 3, ch = c & 7;
                const int r = ch * 8 + r8;
                g = (pl ? Wlo : Whi) + (size_t)(mtile + r) * CC + k0 + ((s ^ (r & 7)) << 3);
                l = (void*)&lA[pl][ch * 8][0];
            } else {                    // B (activations)
                const int c2 = c - 16;
                const int pl = c2 >> 4, ch = c2 & 15;
                const int r = ch * 8 + r8;
                const int kq = k0 + ((s ^ (r & 7)) << 3);
                g = (pl ? Blo : Bhi) + (size_t)(kq >> 5) * (size_t)SS
                                      + (size_t)(ptile + r) * (size_t)RS + (kq & 31);
                l = (void*)&lB[pl][ch * 8][0];
            }
            gl_lds16(g, l);
        }
        __syncthreads();

        #pragma unroll
        for (int ks = 0; ks < 2; ++ks) {
            bf16x8 ah[2], al[2], bh[4], bl[4];
            #pragma unroll
            for (int fm = 0; fm < 2; ++fm) {
                const int r = wm * 32 + fm * 16 + (ln & 15);
                const int col = (((ks * 4 + (ln >> 4)) ^ (r & 7)) << 3);
                ah[fm] = *(const bf16x8*)&lA[0][r][col];
                al[fm] = *(const bf16x8*)&lA[1][r][col];
            }
            #pragma unroll
            for (int fn = 0; fn < 4; ++fn) {
                const int r = wn * 64 + fn * 16 + (ln & 15);
                const int col = (((ks * 4 + (ln >> 4)) ^ (r & 7)) << 3);
                bh[fn] = *(const bf16x8*)&lB[0][r][col];
                bl[fn] = *(const bf16x8*)&lB[1][r][col];
            }
            #pragma unroll
            for (int fm = 0; fm < 2; ++fm)
                #pragma unroll
                for (int fn = 0; fn < 4; ++fn) {
                    acc[fm][fn] = __builtin_amdgcn_mfma_f32_16x16x32_bf16(ah[fm], bh[fn], acc[fm][fn], 0, 0, 0);
                    acc[fm][fn] = __builtin_amdgcn_mfma_f32_16x16x32_bf16(ah[fm], bl[fn], acc[fm][fn], 0, 0, 0);
                    acc[fm][fn] = __builtin_amdgcn_mfma_f32_16x16x32_bf16(al[fm], bh[fn], acc[fm][fn], 0, 0, 0);
                }
        }
        __syncthreads();
    }

    #pragma unroll
    for (int fm = 0; fm < 2; ++fm)
        #pragma unroll
        for (int fn = 0; fn < 4; ++fn)
            #pragma unroll
            for (int r = 0; r < 4; ++r) {
                const int m = mtile + wm * 32 + fm * 16 + (ln >> 4) * 4 + r;
                const int p = ptile + wn * 64 + fn * 16 + (ln & 15);
                C[(size_t)m * ldc + p] = acc[fm][fn][r];
            }
}

// ---------------------------------------------------------------------------
// K2: fused depthwise 3x3 -> depthwise 3x3.  A[576,BH+4,W] -> B[576,BH,W]
// ---------------------------------------------------------------------------
__global__ __launch_bounds__(256) void k2_dwdw(const float* __restrict__ A,
                                               const float* __restrict__ w2,
                                               const float* __restrict__ w3,
                                               float* __restrict__ B,
                                               int h0, int BH) {
    const int tilesW = WW / 32;     // 8
    const int tilesR = BH / 32;
    const int bc = blockIdx.x;
    const int c = bc / (tilesR * tilesW);
    const int rem = bc % (tilesR * tilesW);
    const int r0 = (rem / tilesW) * 32;
    const int w0 = (rem % tilesW) * 32;
    const int t = threadIdx.x;

    __shared__ float in[36][37];
    __shared__ float mid[34][35];

    float w2c[9], w3c[9];
    #pragma unroll
    for (int i = 0; i < 9; ++i) { w2c[i] = w2[c * 9 + i]; w3c[i] = w3[c * 9 + i]; }

    const float* Ac = A + (size_t)c * (BH + 4) * WW;
    for (int e = t; e < 36 * 36; e += 256) {
        int rr = e / 36, cc = e % 36;
        int col = w0 - 2 + cc;
        int arow = r0 + rr;
        in[rr][cc] = (col >= 0 && col < WW) ? Ac[(size_t)arow * WW + col] : 0.f;
    }
    __syncthreads();

    for (int e = t; e < 34 * 34; e += 256) {
        int mr = e / 34, mc = e % 34;
        int grow = h0 + r0 + mr - 1;
        int gcol = w0 + mc - 1;
        float sv = 0.f;
        if (grow >= 0 && grow < HH && gcol >= 0 && gcol < WW) {
            #pragma unroll
            for (int i = 0; i < 3; ++i)
                #pragma unroll
                for (int j = 0; j < 3; ++j)
                    sv = fmaf(in[mr + i][mc + j], w2c[i * 3 + j], sv);
        }
        mid[mr][mc] = sv;
    }
    __syncthreads();

    for (int e = t; e < 32 * 32; e += 256) {
        int rr = e >> 5, cc = e & 31;
        float sv = 0.f;
        #pragma unroll
        for (int i = 0; i < 3; ++i)
            #pragma unroll
            for (int j = 0; j < 3; ++j)
                sv = fmaf(mid[rr + i][cc + j], w3c[i * 3 + j], sv);
        B[((size_t)c * BH + r0 + rr) * WW + w0 + cc] = sv;
    }
}

// ---------------------------------------------------------------------------
// K3 (MFMA): row-wise attention, 64 KB LDS -> 2 blocks/CU.
// Phase A: t<256 stages K (load+norm+split, swizzled); t>=256 stages V
// (permuted columns).  Q fragments come straight from global (L2-hot) with
// the row norm computed via shfl_xor over the 4 lanes sharing a q-row.
// Output written per-block CONTIGUOUS in [head][p][32] split layout.
// ---------------------------------------------------------------------------
__global__ __launch_bounds__(512, 4) void k3_attn_mfma(const float* __restrict__ Bq,
                                                       const float* __restrict__ factor,
                                                       ushort* __restrict__ Ohi,
                                                       ushort* __restrict__ Olo, int BH) {
    const int r = blockIdx.x / NHD;
    const int head = blockIdx.x % NHD;
    const int t = threadIdx.x;
    const size_t plane = (size_t)BH * WW;

    __shared__ __align__(16) char arena[65536];
    ushort* Ksp = (ushort*)arena;            // [2][256 key][32 d], hi @0, lo @8192 (ushort idx)
    ushort* Vt  = (ushort*)(arena + 32768);  // [2][32 d][256 key'] permuted+swizzled
    uint*   Oar = (uint*)arena;              // [2][256][20] epilogue alias (40 KB)

    if (t < 256) {
        // ---- stage K row t: load, normalize, split, swizzled store ----
        const int row = t;
        const float* base = Bq + ((size_t)(CC + head * DH)) * plane + (size_t)r * WW + row;
        float v[32];
        #pragma unroll
        for (int d = 0; d < 32; ++d) v[d] = base[(size_t)d * plane];
        float ss = 0.f;
        #pragma unroll
        for (int d = 0; d < 32; ++d) ss = fmaf(v[d], v[d], ss);
        const float inv = 1.f / fmaxf(sqrtf(ss), 1e-12f);
        const int sw = (row >> 1) & 3;
        #pragma unroll
        for (int d = 0; d < 32; d += 2) {
            float v0 = v[d] * inv, v1 = v[d + 1] * inv;
            ushort h0 = f2b(v0), h1 = f2b(v1);
            ushort g0 = f2b(v0 - b2f(h0)), g1 = f2b(v1 - b2f(h1));
            int dd = (d & 7) | ((((d >> 3) ^ sw) & 3) << 3);
            *(uint*)&Ksp[row * 32 + dd] = (uint)h0 | ((uint)h1 << 16);
            *(uint*)&Ksp[8192 + row * 32 + dd] = (uint)g0 | ((uint)g1 << 16);
        }
    } else {
        // ---- stage V column k (permuted key' = 32s|8g|4b|rr) ----
        const int k = t - 256;
        const int kp = (k & 0xE3) | (((k >> 2) & 3) << 3) | (((k >> 4) & 1) << 2);
        const float* base = Bq + ((size_t)(2 * CC + head * DH)) * plane + (size_t)r * WW + k;
        const int slot = kp >> 3, inb = kp & 7;
        #pragma unroll
        for (int d = 0; d < 32; ++d) {
            float val = base[(size_t)d * plane];
            ushort h = f2b(val);
            ushort g = f2b(val - b2f(h));
            int col = ((slot ^ (d & 7)) << 3) | inb;
            Vt[d * 256 + col] = h;
            Vt[8192 + d * 256 + col] = g;
        }
    }
    __syncthreads();

    const int wv = t >> 6, ln = t & 63;
    const int hig = ln >> 4, lo16 = ln & 15;
    const float fsc = factor[0];

    f32x4 osave[2][2];
    float invl[2];

    #pragma unroll
    for (int c = 0; c < 2; ++c) {
        const int qrow = wv * 32 + c * 16 + lo16;

        // ---- q fragment from global; cooperative norm via shfl ----
        float qv[8];
        {
            const float* qb = Bq + ((size_t)(head * DH + hig * 8)) * plane + (size_t)r * WW + qrow;
            #pragma unroll
            for (int j = 0; j < 8; ++j) qv[j] = qb[(size_t)j * plane];
        }
        float ssq = 0.f;
        #pragma unroll
        for (int j = 0; j < 8; ++j) ssq = fmaf(qv[j], qv[j], ssq);
        ssq += __shfl_xor(ssq, 16);
        ssq += __shfl_xor(ssq, 32);
        const float qinv = fsc / fmaxf(sqrtf(ssq), 1e-12f);
        union { bf16x8 v; uint u[4]; } qh, qlo;
        #pragma unroll
        for (int j = 0; j < 8; j += 2) {
            float v0 = qv[j] * qinv, v1 = qv[j + 1] * qinv;
            ushort h0 = f2b(v0), h1 = f2b(v1);
            ushort g0 = f2b(v0 - b2f(h0)), g1 = f2b(v1 - b2f(h1));
            qh.u[j >> 1] = (uint)h0 | ((uint)h1 << 16);
            qlo.u[j >> 1] = (uint)g0 | ((uint)g1 << 16);
        }

        // ---- S^T: 16 key-frags, split products hh+hl+lh ----
        f32x4 s[16];
        __builtin_amdgcn_s_setprio(1);
        #pragma unroll
        for (int f = 0; f < 16; ++f) {
            const int krow = f * 16 + lo16;
            const int koff = krow * 32 + ((hig ^ ((krow >> 1) & 3)) << 3);
            const bf16x8 kh = *(const bf16x8*)&Ksp[koff];
            const bf16x8 klo = *(const bf16x8*)&Ksp[8192 + koff];
            f32x4 a = {0.f, 0.f, 0.f, 0.f};
            a = __builtin_amdgcn_mfma_f32_16x16x32_bf16(kh, qh.v, a, 0, 0, 0);
            a = __builtin_amdgcn_mfma_f32_16x16x32_bf16(kh, qlo.v, a, 0, 0, 0);
            a = __builtin_amdgcn_mfma_f32_16x16x32_bf16(klo, qh.v, a, 0, 0, 0);
            s[f] = a;
        }
        __builtin_amdgcn_s_setprio(0);

        // ---- softmax (lane holds full row for q = lane&15) ----
        float mx = -3.0e38f;
        #pragma unroll
        for (int f = 0; f < 16; ++f)
            mx = fmaxf(mx, fmaxf(fmaxf(s[f][0], s[f][1]), fmaxf(s[f][2], s[f][3])));
        mx = fmaxf(mx, __shfl_xor(mx, 16));
        mx = fmaxf(mx, __shfl_xor(mx, 32));
        float lsum = 0.f;
        #pragma unroll
        for (int f = 0; f < 16; ++f) {
            #pragma unroll
            for (int rr = 0; rr < 4; ++rr) {
                float p = __expf(s[f][rr] - mx);
                s[f][rr] = p;
                lsum += p;
            }
        }
        lsum += __shfl_xor(lsum, 16);
        lsum += __shfl_xor(lsum, 32);
        invl[c] = 1.f / lsum;

        // ---- pack P to split bf16 (local pairs along regs) ----
        uint phh[16][2], pll[16][2];
        #pragma unroll
        for (int f = 0; f < 16; ++f) {
            ushort h0 = f2b(s[f][0]), h1 = f2b(s[f][1]), h2 = f2b(s[f][2]), h3 = f2b(s[f][3]);
            phh[f][0] = (uint)h0 | ((uint)h1 << 16);
            phh[f][1] = (uint)h2 | ((uint)h3 << 16);
            ushort g0 = f2b(s[f][0] - b2f(h0)), g1 = f2b(s[f][1] - b2f(h1));
            ushort g2 = f2b(s[f][2] - b2f(h2)), g3 = f2b(s[f][3] - b2f(h3));
            pll[f][0] = (uint)g0 | ((uint)g1 << 16);
            pll[f][1] = (uint)g2 | ((uint)g3 << 16);
        }

        // ---- PV over permuted key order: out^T = V^T x P^T ----
        f32x4 o0a = {0,0,0,0}, o0b = {0,0,0,0}, o1a = {0,0,0,0}, o1b = {0,0,0,0};
        __builtin_amdgcn_s_setprio(1);
        #pragma unroll
        for (int st = 0; st < 8; ++st) {
            union { bf16x8 v; uint u[4]; } pbh, pbl;
            pbh.u[0] = phh[2*st][0];   pbh.u[1] = phh[2*st][1];
            pbh.u[2] = phh[2*st+1][0]; pbh.u[3] = phh[2*st+1][1];
            pbl.u[0] = pll[2*st][0];   pbl.u[1] = pll[2*st][1];
            pbl.u[2] = pll[2*st+1][0]; pbl.u[3] = pll[2*st+1][1];
            {
                const int drow = lo16;
                const int voff = drow * 256 + (((4*st + hig) ^ (drow & 7)) << 3);
                const bf16x8 vh = *(const bf16x8*)&Vt[voff];
                const bf16x8 vl = *(const bf16x8*)&Vt[8192 + voff];
                f32x4& o = (st & 1) ? o0b : o0a;
                o = __builtin_amdgcn_mfma_f32_16x16x32_bf16(vh, pbh.v, o, 0, 0, 0);
                o = __builtin_amdgcn_mfma_f32_16x16x32_bf16(vh, pbl.v, o, 0, 0, 0);
                o = __builtin_amdgcn_mfma_f32_16x16x32_bf16(vl, pbh.v, o, 0, 0, 0);
            }
            {
                const int drow = 16 + lo16;
                const int voff = drow * 256 + (((4*st + hig) ^ (drow & 7)) << 3);
                const bf16x8 vh = *(const bf16x8*)&Vt[voff];
                const bf16x8 vl = *(const bf16x8*)&Vt[8192 + voff];
                f32x4& o = (st & 1) ? o1b : o1a;
                o = __builtin_amdgcn_mfma_f32_16x16x32_bf16(vh, pbh.v, o, 0, 0, 0);
                o = __builtin_amdgcn_mfma_f32_16x16x32_bf16(vh, pbl.v, o, 0, 0, 0);
                o = __builtin_amdgcn_mfma_f32_16x16x32_bf16(vl, pbh.v, o, 0, 0, 0);
            }
        }
        __builtin_amdgcn_s_setprio(0);
        #pragma unroll
        for (int rr = 0; rr < 4; ++rr) { o0a[rr] += o0b[rr]; o1a[rr] += o1b[rr]; }
        osave[c][0] = o0a;
        osave[c][1] = o1a;
    }

    __syncthreads();   // all waves done reading Ksp/Vt before Oar overwrite

    // ---- scale + split + transpose through LDS ----
    #pragma unroll
    for (int c = 0; c < 2; ++c) {
        const int qrow = wv * 32 + c * 16 + lo16;
        #pragma unroll
        for (int fm = 0; fm < 2; ++fm) {
            const f32x4 o = osave[c][fm];
            const float s0 = o[0] * invl[c], s1 = o[1] * invl[c];
            const float s2 = o[2] * invl[c], s3 = o[3] * invl[c];
            const ushort h0 = f2b(s0), h1 = f2b(s1), h2 = f2b(s2), h3 = f2b(s3);
            const ushort g0 = f2b(s0 - b2f(h0)), g1 = f2b(s1 - b2f(h1));
            const ushort g2 = f2b(s2 - b2f(h2)), g3 = f2b(s3 - b2f(h3));
            const int dp = 8 * fm + 2 * hig;           // u32 index of d-pair
            Oar[qrow * 20 + dp]            = (uint)h0 | ((uint)h1 << 16);
            Oar[qrow * 20 + dp + 1]        = (uint)h2 | ((uint)h3 << 16);
            Oar[5120 + qrow * 20 + dp]     = (uint)g0 | ((uint)g1 << 16);
            Oar[5120 + qrow * 20 + dp + 1] = (uint)g2 | ((uint)g3 << 16);
        }
    }
    __syncthreads();

    // ---- per-block contiguous writes: O[head][r*256+t][32] split planes ----
    if (t < 256) {
        const size_t obase = ((size_t)head * (size_t)BH * WW + (size_t)r * WW + t) * DH;
        uint4* dh_ = (uint4*)(Ohi + obase);
        uint4* dl_ = (uint4*)(Olo + obase);
        const uint* srcH = &Oar[t * 20];
        const uint* srcL = &Oar[5120 + t * 20];
        #pragma unroll
        for (int i = 0; i < 4; ++i) {
            dh_[i] = *(const uint4*)&srcH[i * 4];
            dl_[i] = *(const uint4*)&srcL[i * 4];
        }
    }
}

extern "C" void kernel_launch(void* const* d_in, const int* in_sizes, int n_in,
                              void* d_out, int out_size, void* d_ws, size_t ws_size,
                              hipStream_t stream) {
    const float* x      = (const float*)d_in[0];
    const float* w1     = (const float*)d_in[1];
    const float* w2     = (const float*)d_in[2];
    const float* w3     = (const float*)d_in[3];
    const float* factor = (const float*)d_in[4];
    const float* wf     = (const float*)d_in[5];
    float* out = (float*)d_out;

    const size_t SW = (size_t)(C3 + CC) * CC * 2 * sizeof(ushort);   // w splits (hi+lo)
    int BH = 128;
    while (BH > 32) {
        size_t SA = (size_t)C3 * (BH + 4) * WW * 4;
        size_t SB = (size_t)C3 * BH * WW * 4;
        if (SA + SB + SW <= ws_size) break;
        BH >>= 1;
    }
    const size_t SA = (size_t)C3 * (BH + 4) * WW * 4;
    const size_t SB = (size_t)C3 * BH * WW * 4;

    float*  A   = (float*)d_ws;                            // qkv1 region; later O hi/lo
    float*  Bq  = (float*)((char*)d_ws + SA);              // qkv3 region; earlier Xt hi/lo
    ushort* Wsp = (ushort*)((char*)d_ws + SA + SB);        // weight splits
    ushort* Whi = Wsp;                                     // [768][192]
    ushort* Wlo = Wsp + (size_t)(C3 + CC) * CC;

    ushort* Xhi = (ushort*)Bq;                             // [(BH+4)*256][192]
    ushort* Xlo = Xhi + (size_t)(BH + 4) * WW * CC;
    ushort* Ohi = (ushort*)A;                              // [6][BH*256][32]
    ushort* Olo = Ohi + (size_t)NHD * BH * WW * DH;

    prep_w<<<dim3((C3 + CC) * CC / 256), dim3(256), 0, stream>>>(w1, wf, Whi, Wlo);

    for (int n = 0; n < NB; ++n) {
        for (int h0 = 0; h0 < HH; h0 += BH) {
            prep_xt<<<dim3((BH + 4) * (WW / 64)), dim3(256), 0, stream>>>(x, Xhi, Xlo, n, h0, BH);
            gemm_split<<<dim3((BH + 4) * WW / 128, C3 / 64), dim3(256), 0, stream>>>(
                Whi, Wlo, Xhi, Xlo, A, (BH + 4) * WW, CC, DH);
            k2_dwdw<<<dim3(C3 * (BH / 32) * (WW / 32)), dim3(256), 0, stream>>>(A, w2, w3, Bq, h0, BH);
            k3_attn_mfma<<<dim3(NHD * BH), dim3(512), 0, stream>>>(Bq, factor, Ohi, Olo, BH);
            gemm_split<<<dim3(BH * WW / 128, CC / 64), dim3(256), 0, stream>>>(
                Whi + (size_t)C3 * CC, Wlo + (size_t)C3 * CC, Ohi, Olo,
                out + ((size_t)n * CC) * HH * WW + (size_t)h0 * WW, HH * WW,
                DH, BH * WW * DH);
        }
    }
}

// Round 6
// 585.266 us; speedup vs baseline: 2.8498x; 1.1531x over previous
//
#include <hip/hip_runtime.h>
#include <hip/hip_bf16.h>
#include <math.h>

#define NB 2
#define CC 192
#define HH 256
#define WW 256
#define NHD 6
#define DH 32
#define C3 576   // 3*CC

typedef __attribute__((ext_vector_type(8))) short bf16x8;
typedef __attribute__((ext_vector_type(4))) float f32x4;

__device__ __forceinline__ ushort f2b(float v) {
    __hip_bfloat16 b = __float2bfloat16(v);
    return *reinterpret_cast<ushort*>(&b);
}
__device__ __forceinline__ float b2f(ushort u) {
    __hip_bfloat16 b;
    *reinterpret_cast<ushort*>(&b) = u;
    return __bfloat162float(b);
}

__device__ __forceinline__ void gl_lds16(const void* g, void* l) {
    __builtin_amdgcn_global_load_lds((const __attribute__((address_space(1))) void*)g,
                                     (__attribute__((address_space(3))) void*)l, 16, 0, 0);
}

// ---------------------------------------------------------------------------
// prep_w: split w1[576x192] and wf[192x192] fp32 -> bf16 hi/lo planes.
// ---------------------------------------------------------------------------
__global__ __launch_bounds__(256) void prep_w(const float* __restrict__ w1,
                                              const float* __restrict__ wf,
                                              ushort* __restrict__ Whi,
                                              ushort* __restrict__ Wlo) {
    int i = blockIdx.x * 256 + threadIdx.x;       // < 147456
    float v = (i < C3 * CC) ? w1[i] : wf[i - C3 * CC];
    ushort h = f2b(v);
    Whi[i] = h;
    Wlo[i] = f2b(v - b2f(h));
}

// ---------------------------------------------------------------------------
// prep_xt: transpose+split band of x -> Xt[p][k] bf16 hi/lo, p = a*256+w.
// ---------------------------------------------------------------------------
__global__ __launch_bounds__(256) void prep_xt(const float* __restrict__ x,
                                               ushort* __restrict__ Xhi,
                                               ushort* __restrict__ Xlo,
                                               int n, int h0, int BH) {
    const int p0 = blockIdx.x * 64;
    const int gh = h0 - 2 + (p0 >> 8);
    const int wcol = p0 & 255;
    const int t = threadIdx.x;

    if (gh < 0 || gh >= HH) {
        uint* H = (uint*)(Xhi + (size_t)p0 * CC);
        uint* L = (uint*)(Xlo + (size_t)p0 * CC);
        for (int e = t; e < 64 * CC / 2; e += 256) { H[e] = 0u; L[e] = 0u; }
        return;
    }

    __shared__ float xs[CC][65];
    const float* xb = x + ((size_t)n * CC) * (HH * WW) + (size_t)gh * WW + wcol;
    for (int e = t; e < CC * 16; e += 256) {
        int ic = e >> 4, j = e & 15;
        float4 v = *(const float4*)(xb + (size_t)ic * (HH * WW) + j * 4);
        xs[ic][j * 4 + 0] = v.x;
        xs[ic][j * 4 + 1] = v.y;
        xs[ic][j * 4 + 2] = v.z;
        xs[ic][j * 4 + 3] = v.w;
    }
    __syncthreads();

    const int r = t >> 2;            // local position 0..63
    const int k0 = (t & 3) * 48;     // k-chunk
    size_t orow = ((size_t)p0 + r) * CC + k0;
    uint* H = (uint*)(Xhi + orow);
    uint* L = (uint*)(Xlo + orow);
    #pragma unroll
    for (int j = 0; j < 48; j += 2) {
        float va = xs[k0 + j][r], vb = xs[k0 + j + 1][r];
        ushort ha = f2b(va), hb = f2b(vb);
        ushort la = f2b(va - b2f(ha)), lb = f2b(vb - b2f(hb));
        H[j >> 1] = (uint)ha | ((uint)hb << 16);
        L[j >> 1] = (uint)la | ((uint)lb << 16);
    }
}

// ---------------------------------------------------------------------------
// gemm_split: C[M][N] = W[M][192] * B[192][N], split-bf16 (hh + hl + lh).
// 1-D grid with XCD-chunked bijective swizzle: xcd = bid%8 owns a contiguous
// ptile chunk, m-fastest within it -> the NM blocks sharing a B-panel run
// back-to-back on ONE XCD (B stays L2-hot; kills the NMx B re-fetch).
// Requires NP % 8 == 0 (holds: 520/264 for K1, 512/256 for K4).
// B element (p, k) at: Bpl + (k>>5)*SS + p*RS + (k&31).
//   K1 (Xt [p][192]):      RS=192, SS=32
//   K4 (O  [head][p][32]): RS=32,  SS=BH*256*32
// ---------------------------------------------------------------------------
__global__ __launch_bounds__(256) void gemm_split(const ushort* __restrict__ Whi,
                                                  const ushort* __restrict__ Wlo,
                                                  const ushort* __restrict__ Bhi,
                                                  const ushort* __restrict__ Blo,
                                                  float* __restrict__ C, int ldc,
                                                  int RS, int SS, int NM) {
    __shared__ ushort lA[2][64][64];    // [plane][m][k]  16 KB
    __shared__ ushort lB[2][128][64];   // [plane][p][k]  32 KB

    const int bid = blockIdx.x;
    const int xcd = bid & 7;
    const int idx = bid >> 3;
    const int ptpx = (int)(gridDim.x >> 3) / NM;   // ptiles per XCD
    const int mtile = (idx % NM) * 64;
    const int ptile = (xcd * ptpx + idx / NM) * 128;

    const int t = threadIdx.x, wv = t >> 6, ln = t & 63;
    const int wm = wv >> 1, wn = wv & 1;

    f32x4 zero = {0.f, 0.f, 0.f, 0.f};
    f32x4 acc[2][4];
    #pragma unroll
    for (int fm = 0; fm < 2; ++fm)
        #pragma unroll
        for (int fn = 0; fn < 4; ++fn) acc[fm][fn] = zero;

    const int r8 = ln >> 3, s = ln & 7;

    for (int kk = 0; kk < 3; ++kk) {
        const int k0 = kk * 64;
        #pragma unroll
        for (int ci = 0; ci < 12; ++ci) {
            const int c = wv * 12 + ci;
            const ushort* g;
            void* l;
            if (c < 16) {               // A (weights)
                const int pl = c >> 3, ch = c & 7;
                const int r = ch * 8 + r8;
                g = (pl ? Wlo : Whi) + (size_t)(mtile + r) * CC + k0 + ((s ^ (r & 7)) << 3);
                l = (void*)&lA[pl][ch * 8][0];
            } else {                    // B (activations)
                const int c2 = c - 16;
                const int pl = c2 >> 4, ch = c2 & 15;
                const int r = ch * 8 + r8;
                const int kq = k0 + ((s ^ (r & 7)) << 3);
                g = (pl ? Blo : Bhi) + (size_t)(kq >> 5) * (size_t)SS
                                      + (size_t)(ptile + r) * (size_t)RS + (kq & 31);
                l = (void*)&lB[pl][ch * 8][0];
            }
            gl_lds16(g, l);
        }
        __syncthreads();

        #pragma unroll
        for (int ks = 0; ks < 2; ++ks) {
            bf16x8 ah[2], al[2], bh[4], bl[4];
            #pragma unroll
            for (int fm = 0; fm < 2; ++fm) {
                const int r = wm * 32 + fm * 16 + (ln & 15);
                const int col = (((ks * 4 + (ln >> 4)) ^ (r & 7)) << 3);
                ah[fm] = *(const bf16x8*)&lA[0][r][col];
                al[fm] = *(const bf16x8*)&lA[1][r][col];
            }
            #pragma unroll
            for (int fn = 0; fn < 4; ++fn) {
                const int r = wn * 64 + fn * 16 + (ln & 15);
                const int col = (((ks * 4 + (ln >> 4)) ^ (r & 7)) << 3);
                bh[fn] = *(const bf16x8*)&lB[0][r][col];
                bl[fn] = *(const bf16x8*)&lB[1][r][col];
            }
            #pragma unroll
            for (int fm = 0; fm < 2; ++fm)
                #pragma unroll
                for (int fn = 0; fn < 4; ++fn) {
                    acc[fm][fn] = __builtin_amdgcn_mfma_f32_16x16x32_bf16(ah[fm], bh[fn], acc[fm][fn], 0, 0, 0);
                    acc[fm][fn] = __builtin_amdgcn_mfma_f32_16x16x32_bf16(ah[fm], bl[fn], acc[fm][fn], 0, 0, 0);
                    acc[fm][fn] = __builtin_amdgcn_mfma_f32_16x16x32_bf16(al[fm], bh[fn], acc[fm][fn], 0, 0, 0);
                }
        }
        __syncthreads();
    }

    #pragma unroll
    for (int fm = 0; fm < 2; ++fm)
        #pragma unroll
        for (int fn = 0; fn < 4; ++fn)
            #pragma unroll
            for (int r = 0; r < 4; ++r) {
                const int m = mtile + wm * 32 + fm * 16 + (ln >> 4) * 4 + r;
                const int p = ptile + wn * 64 + fn * 16 + (ln & 15);
                C[(size_t)m * ldc + p] = acc[fm][fn][r];
            }
}

// ---------------------------------------------------------------------------
// K2: fused depthwise 3x3 -> depthwise 3x3.  A[576,BH+4,W] -> B[576,BH,W]
// ---------------------------------------------------------------------------
__global__ __launch_bounds__(256) void k2_dwdw(const float* __restrict__ A,
                                               const float* __restrict__ w2,
                                               const float* __restrict__ w3,
                                               float* __restrict__ B,
                                               int h0, int BH) {
    const int tilesW = WW / 32;     // 8
    const int tilesR = BH / 32;
    const int bc = blockIdx.x;
    const int c = bc / (tilesR * tilesW);
    const int rem = bc % (tilesR * tilesW);
    const int r0 = (rem / tilesW) * 32;
    const int w0 = (rem % tilesW) * 32;
    const int t = threadIdx.x;

    __shared__ float in[36][37];
    __shared__ float mid[34][35];

    float w2c[9], w3c[9];
    #pragma unroll
    for (int i = 0; i < 9; ++i) { w2c[i] = w2[c * 9 + i]; w3c[i] = w3[c * 9 + i]; }

    const float* Ac = A + (size_t)c * (BH + 4) * WW;
    for (int e = t; e < 36 * 36; e += 256) {
        int rr = e / 36, cc = e % 36;
        int col = w0 - 2 + cc;
        int arow = r0 + rr;
        in[rr][cc] = (col >= 0 && col < WW) ? Ac[(size_t)arow * WW + col] : 0.f;
    }
    __syncthreads();

    for (int e = t; e < 34 * 34; e += 256) {
        int mr = e / 34, mc = e % 34;
        int grow = h0 + r0 + mr - 1;
        int gcol = w0 + mc - 1;
        float sv = 0.f;
        if (grow >= 0 && grow < HH && gcol >= 0 && gcol < WW) {
            #pragma unroll
            for (int i = 0; i < 3; ++i)
                #pragma unroll
                for (int j = 0; j < 3; ++j)
                    sv = fmaf(in[mr + i][mc + j], w2c[i * 3 + j], sv);
        }
        mid[mr][mc] = sv;
    }
    __syncthreads();

    for (int e = t; e < 32 * 32; e += 256) {
        int rr = e >> 5, cc = e & 31;
        float sv = 0.f;
        #pragma unroll
        for (int i = 0; i < 3; ++i)
            #pragma unroll
            for (int j = 0; j < 3; ++j)
                sv = fmaf(mid[rr + i][cc + j], w3c[i * 3 + j], sv);
        B[((size_t)c * BH + r0 + rr) * WW + w0 + cc] = sv;
    }
}

// ---------------------------------------------------------------------------
// K3 (MFMA): row-wise attention, 64 KB LDS -> 2 blocks/CU.
// ---------------------------------------------------------------------------
__global__ __launch_bounds__(512, 4) void k3_attn_mfma(const float* __restrict__ Bq,
                                                       const float* __restrict__ factor,
                                                       ushort* __restrict__ Ohi,
                                                       ushort* __restrict__ Olo, int BH) {
    const int r = blockIdx.x / NHD;
    const int head = blockIdx.x % NHD;
    const int t = threadIdx.x;
    const size_t plane = (size_t)BH * WW;

    __shared__ __align__(16) char arena[65536];
    ushort* Ksp = (ushort*)arena;            // [2][256 key][32 d], hi @0, lo @8192 (ushort idx)
    ushort* Vt  = (ushort*)(arena + 32768);  // [2][32 d][256 key'] permuted+swizzled
    uint*   Oar = (uint*)arena;              // [2][256][20] epilogue alias (40 KB)

    if (t < 256) {
        // ---- stage K row t: load, normalize, split, swizzled store ----
        const int row = t;
        const float* base = Bq + ((size_t)(CC + head * DH)) * plane + (size_t)r * WW + row;
        float v[32];
        #pragma unroll
        for (int d = 0; d < 32; ++d) v[d] = base[(size_t)d * plane];
        float ss = 0.f;
        #pragma unroll
        for (int d = 0; d < 32; ++d) ss = fmaf(v[d], v[d], ss);
        const float inv = 1.f / fmaxf(sqrtf(ss), 1e-12f);
        const int sw = (row >> 1) & 3;
        #pragma unroll
        for (int d = 0; d < 32; d += 2) {
            float v0 = v[d] * inv, v1 = v[d + 1] * inv;
            ushort h0 = f2b(v0), h1 = f2b(v1);
            ushort g0 = f2b(v0 - b2f(h0)), g1 = f2b(v1 - b2f(h1));
            int dd = (d & 7) | ((((d >> 3) ^ sw) & 3) << 3);
            *(uint*)&Ksp[row * 32 + dd] = (uint)h0 | ((uint)h1 << 16);
            *(uint*)&Ksp[8192 + row * 32 + dd] = (uint)g0 | ((uint)g1 << 16);
        }
    } else {
        // ---- stage V column k (permuted key' = 32s|8g|4b|rr) ----
        const int k = t - 256;
        const int kp = (k & 0xE3) | (((k >> 2) & 3) << 3) | (((k >> 4) & 1) << 2);
        const float* base = Bq + ((size_t)(2 * CC + head * DH)) * plane + (size_t)r * WW + k;
        const int slot = kp >> 3, inb = kp & 7;
        #pragma unroll
        for (int d = 0; d < 32; ++d) {
            float val = base[(size_t)d * plane];
            ushort h = f2b(val);
            ushort g = f2b(val - b2f(h));
            int col = ((slot ^ (d & 7)) << 3) | inb;
            Vt[d * 256 + col] = h;
            Vt[8192 + d * 256 + col] = g;
        }
    }
    __syncthreads();

    const int wv = t >> 6, ln = t & 63;
    const int hig = ln >> 4, lo16 = ln & 15;
    const float fsc = factor[0];

    f32x4 osave[2][2];
    float invl[2];

    #pragma unroll
    for (int c = 0; c < 2; ++c) {
        const int qrow = wv * 32 + c * 16 + lo16;

        // ---- q fragment from global; cooperative norm via shfl ----
        float qv[8];
        {
            const float* qb = Bq + ((size_t)(head * DH + hig * 8)) * plane + (size_t)r * WW + qrow;
            #pragma unroll
            for (int j = 0; j < 8; ++j) qv[j] = qb[(size_t)j * plane];
        }
        float ssq = 0.f;
        #pragma unroll
        for (int j = 0; j < 8; ++j) ssq = fmaf(qv[j], qv[j], ssq);
        ssq += __shfl_xor(ssq, 16);
        ssq += __shfl_xor(ssq, 32);
        const float qinv = fsc / fmaxf(sqrtf(ssq), 1e-12f);
        union { bf16x8 v; uint u[4]; } qh, qlo;
        #pragma unroll
        for (int j = 0; j < 8; j += 2) {
            float v0 = qv[j] * qinv, v1 = qv[j + 1] * qinv;
            ushort h0 = f2b(v0), h1 = f2b(v1);
            ushort g0 = f2b(v0 - b2f(h0)), g1 = f2b(v1 - b2f(h1));
            qh.u[j >> 1] = (uint)h0 | ((uint)h1 << 16);
            qlo.u[j >> 1] = (uint)g0 | ((uint)g1 << 16);
        }

        // ---- S^T: 16 key-frags, split products hh+hl+lh ----
        f32x4 s[16];
        __builtin_amdgcn_s_setprio(1);
        #pragma unroll
        for (int f = 0; f < 16; ++f) {
            const int krow = f * 16 + lo16;
            const int koff = krow * 32 + ((hig ^ ((krow >> 1) & 3)) << 3);
            const bf16x8 kh = *(const bf16x8*)&Ksp[koff];
            const bf16x8 klo = *(const bf16x8*)&Ksp[8192 + koff];
            f32x4 a = {0.f, 0.f, 0.f, 0.f};
            a = __builtin_amdgcn_mfma_f32_16x16x32_bf16(kh, qh.v, a, 0, 0, 0);
            a = __builtin_amdgcn_mfma_f32_16x16x32_bf16(kh, qlo.v, a, 0, 0, 0);
            a = __builtin_amdgcn_mfma_f32_16x16x32_bf16(klo, qh.v, a, 0, 0, 0);
            s[f] = a;
        }
        __builtin_amdgcn_s_setprio(0);

        // ---- softmax (lane holds full row for q = lane&15) ----
        float mx = -3.0e38f;
        #pragma unroll
        for (int f = 0; f < 16; ++f)
            mx = fmaxf(mx, fmaxf(fmaxf(s[f][0], s[f][1]), fmaxf(s[f][2], s[f][3])));
        mx = fmaxf(mx, __shfl_xor(mx, 16));
        mx = fmaxf(mx, __shfl_xor(mx, 32));
        float lsum = 0.f;
        #pragma unroll
        for (int f = 0; f < 16; ++f) {
            #pragma unroll
            for (int rr = 0; rr < 4; ++rr) {
                float p = __expf(s[f][rr] - mx);
                s[f][rr] = p;
                lsum += p;
            }
        }
        lsum += __shfl_xor(lsum, 16);
        lsum += __shfl_xor(lsum, 32);
        invl[c] = 1.f / lsum;

        // ---- pack P to split bf16 (local pairs along regs) ----
        uint phh[16][2], pll[16][2];
        #pragma unroll
        for (int f = 0; f < 16; ++f) {
            ushort h0 = f2b(s[f][0]), h1 = f2b(s[f][1]), h2 = f2b(s[f][2]), h3 = f2b(s[f][3]);
            phh[f][0] = (uint)h0 | ((uint)h1 << 16);
            phh[f][1] = (uint)h2 | ((uint)h3 << 16);
            ushort g0 = f2b(s[f][0] - b2f(h0)), g1 = f2b(s[f][1] - b2f(h1));
            ushort g2 = f2b(s[f][2] - b2f(h2)), g3 = f2b(s[f][3] - b2f(h3));
            pll[f][0] = (uint)g0 | ((uint)g1 << 16);
            pll[f][1] = (uint)g2 | ((uint)g3 << 16);
        }

        // ---- PV over permuted key order: out^T = V^T x P^T ----
        f32x4 o0a = {0,0,0,0}, o0b = {0,0,0,0}, o1a = {0,0,0,0}, o1b = {0,0,0,0};
        __builtin_amdgcn_s_setprio(1);
        #pragma unroll
        for (int st = 0; st < 8; ++st) {
            union { bf16x8 v; uint u[4]; } pbh, pbl;
            pbh.u[0] = phh[2*st][0];   pbh.u[1] = phh[2*st][1];
            pbh.u[2] = phh[2*st+1][0]; pbh.u[3] = phh[2*st+1][1];
            pbl.u[0] = pll[2*st][0];   pbl.u[1] = pll[2*st][1];
            pbl.u[2] = pll[2*st+1][0]; pbl.u[3] = pll[2*st+1][1];
            {
                const int drow = lo16;
                const int voff = drow * 256 + (((4*st + hig) ^ (drow & 7)) << 3);
                const bf16x8 vh = *(const bf16x8*)&Vt[voff];
                const bf16x8 vl = *(const bf16x8*)&Vt[8192 + voff];
                f32x4& o = (st & 1) ? o0b : o0a;
                o = __builtin_amdgcn_mfma_f32_16x16x32_bf16(vh, pbh.v, o, 0, 0, 0);
                o = __builtin_amdgcn_mfma_f32_16x16x32_bf16(vh, pbl.v, o, 0, 0, 0);
                o = __builtin_amdgcn_mfma_f32_16x16x32_bf16(vl, pbh.v, o, 0, 0, 0);
            }
            {
                const int drow = 16 + lo16;
                const int voff = drow * 256 + (((4*st + hig) ^ (drow & 7)) << 3);
                const bf16x8 vh = *(const bf16x8*)&Vt[voff];
                const bf16x8 vl = *(const bf16x8*)&Vt[8192 + voff];
                f32x4& o = (st & 1) ? o1b : o1a;
                o = __builtin_amdgcn_mfma_f32_16x16x32_bf16(vh, pbh.v, o, 0, 0, 0);
                o = __builtin_amdgcn_mfma_f32_16x16x32_bf16(vh, pbl.v, o, 0, 0, 0);
                o = __builtin_amdgcn_mfma_f32_16x16x32_bf16(vl, pbh.v, o, 0, 0, 0);
            }
        }
        __builtin_amdgcn_s_setprio(0);
        #pragma unroll
        for (int rr = 0; rr < 4; ++rr) { o0a[rr] += o0b[rr]; o1a[rr] += o1b[rr]; }
        osave[c][0] = o0a;
        osave[c][1] = o1a;
    }

    __syncthreads();   // all waves done reading Ksp/Vt before Oar overwrite

    // ---- scale + split + transpose through LDS ----
    #pragma unroll
    for (int c = 0; c < 2; ++c) {
        const int qrow = wv * 32 + c * 16 + lo16;
        #pragma unroll
        for (int fm = 0; fm < 2; ++fm) {
            const f32x4 o = osave[c][fm];
            const float s0 = o[0] * invl[c], s1 = o[1] * invl[c];
            const float s2 = o[2] * invl[c], s3 = o[3] * invl[c];
            const ushort h0 = f2b(s0), h1 = f2b(s1), h2 = f2b(s2), h3 = f2b(s3);
            const ushort g0 = f2b(s0 - b2f(h0)), g1 = f2b(s1 - b2f(h1));
            const ushort g2 = f2b(s2 - b2f(h2)), g3 = f2b(s3 - b2f(h3));
            const int dp = 8 * fm + 2 * hig;           // u32 index of d-pair
            Oar[qrow * 20 + dp]            = (uint)h0 | ((uint)h1 << 16);
            Oar[qrow * 20 + dp + 1]        = (uint)h2 | ((uint)h3 << 16);
            Oar[5120 + qrow * 20 + dp]     = (uint)g0 | ((uint)g1 << 16);
            Oar[5120 + qrow * 20 + dp + 1] = (uint)g2 | ((uint)g3 << 16);
        }
    }
    __syncthreads();

    // ---- per-block contiguous writes: O[head][r*256+t][32] split planes ----
    if (t < 256) {
        const size_t obase = ((size_t)head * (size_t)BH * WW + (size_t)r * WW + t) * DH;
        uint4* dh_ = (uint4*)(Ohi + obase);
        uint4* dl_ = (uint4*)(Olo + obase);
        const uint* srcH = &Oar[t * 20];
        const uint* srcL = &Oar[5120 + t * 20];
        #pragma unroll
        for (int i = 0; i < 4; ++i) {
            dh_[i] = *(const uint4*)&srcH[i * 4];
            dl_[i] = *(const uint4*)&srcL[i * 4];
        }
    }
}

extern "C" void kernel_launch(void* const* d_in, const int* in_sizes, int n_in,
                              void* d_out, int out_size, void* d_ws, size_t ws_size,
                              hipStream_t stream) {
    const float* x      = (const float*)d_in[0];
    const float* w1     = (const float*)d_in[1];
    const float* w2     = (const float*)d_in[2];
    const float* w3     = (const float*)d_in[3];
    const float* factor = (const float*)d_in[4];
    const float* wf     = (const float*)d_in[5];
    float* out = (float*)d_out;

    const size_t SW = (size_t)(C3 + CC) * CC * 2 * sizeof(ushort);   // w splits (hi+lo)
    int BH = 256;                       // full image per batch if ws allows (~305 MB)
    while (BH > 32) {
        size_t SA_ = (size_t)C3 * (BH + 4) * WW * 4;
        size_t SB_ = (size_t)C3 * BH * WW * 4;
        if (SA_ + SB_ + SW <= ws_size) break;
        BH >>= 1;
    }
    const size_t SA = (size_t)C3 * (BH + 4) * WW * 4;
    const size_t SB = (size_t)C3 * BH * WW * 4;

    float*  A   = (float*)d_ws;                            // qkv1 region; later O hi/lo
    float*  Bq  = (float*)((char*)d_ws + SA);              // qkv3 region; earlier Xt hi/lo
    ushort* Wsp = (ushort*)((char*)d_ws + SA + SB);        // weight splits
    ushort* Whi = Wsp;                                     // [768][192]
    ushort* Wlo = Wsp + (size_t)(C3 + CC) * CC;

    ushort* Xhi = (ushort*)Bq;                             // [(BH+4)*256][192]
    ushort* Xlo = Xhi + (size_t)(BH + 4) * WW * CC;
    ushort* Ohi = (ushort*)A;                              // [6][BH*256][32]
    ushort* Olo = Ohi + (size_t)NHD * BH * WW * DH;

    prep_w<<<dim3((C3 + CC) * CC / 256), dim3(256), 0, stream>>>(w1, wf, Whi, Wlo);

    for (int n = 0; n < NB; ++n) {
        for (int h0 = 0; h0 < HH; h0 += BH) {
            prep_xt<<<dim3((BH + 4) * (WW / 64)), dim3(256), 0, stream>>>(x, Xhi, Xlo, n, h0, BH);
            gemm_split<<<dim3(((BH + 4) * WW / 128) * (C3 / 64)), dim3(256), 0, stream>>>(
                Whi, Wlo, Xhi, Xlo, A, (BH + 4) * WW, CC, DH, C3 / 64);
            k2_dwdw<<<dim3(C3 * (BH / 32) * (WW / 32)), dim3(256), 0, stream>>>(A, w2, w3, Bq, h0, BH);
            k3_attn_mfma<<<dim3(NHD * BH), dim3(512), 0, stream>>>(Bq, factor, Ohi, Olo, BH);
            gemm_split<<<dim3((BH * WW / 128) * (CC / 64)), dim3(256), 0, stream>>>(
                Whi + (size_t)C3 * CC, Wlo + (size_t)C3 * CC, Ohi, Olo,
                out + ((size_t)n * CC) * HH * WW + (size_t)h0 * WW, HH * WW,
                DH, BH * WW * DH, CC / 64);
        }
    }
}

// Round 7
// 541.148 us; speedup vs baseline: 3.0822x; 1.0815x over previous
//
#include <hip/hip_runtime.h>
#include <hip/hip_bf16.h>
#include <math.h>

#define NB 2
#define CC 192
#define HH 256
#define WW 256
#define NHD 6
#define DH 32
#define C3 576   // 3*CC

typedef __attribute__((ext_vector_type(8))) short bf16x8;
typedef __attribute__((ext_vector_type(4))) float f32x4;

__device__ __forceinline__ ushort f2b(float v) {
    __hip_bfloat16 b = __float2bfloat16(v);
    return *reinterpret_cast<ushort*>(&b);
}
__device__ __forceinline__ float b2f(ushort u) {
    __hip_bfloat16 b;
    *reinterpret_cast<ushort*>(&b) = u;
    return __bfloat162float(b);
}

__device__ __forceinline__ void gl_lds16(const void* g, void* l) {
    __builtin_amdgcn_global_load_lds((const __attribute__((address_space(1))) void*)g,
                                     (__attribute__((address_space(3))) void*)l, 16, 0, 0);
}

// ---------------------------------------------------------------------------
// prep_w: split w1[576x192] and wf[192x192] fp32 -> bf16 hi/lo planes.
// ---------------------------------------------------------------------------
__global__ __launch_bounds__(256) void prep_w(const float* __restrict__ w1,
                                              const float* __restrict__ wf,
                                              ushort* __restrict__ Whi,
                                              ushort* __restrict__ Wlo) {
    int i = blockIdx.x * 256 + threadIdx.x;       // < 147456
    float v = (i < C3 * CC) ? w1[i] : wf[i - C3 * CC];
    ushort h = f2b(v);
    Whi[i] = h;
    Wlo[i] = f2b(v - b2f(h));
}

// ---------------------------------------------------------------------------
// prep_xt: transpose+split band of x -> Xt[p][k] bf16 hi/lo, p = a*256+w.
// ---------------------------------------------------------------------------
__global__ __launch_bounds__(256) void prep_xt(const float* __restrict__ x,
                                               ushort* __restrict__ Xhi,
                                               ushort* __restrict__ Xlo,
                                               int n, int h0, int BH) {
    const int p0 = blockIdx.x * 64;
    const int gh = h0 - 2 + (p0 >> 8);
    const int wcol = p0 & 255;
    const int t = threadIdx.x;

    if (gh < 0 || gh >= HH) {
        uint* H = (uint*)(Xhi + (size_t)p0 * CC);
        uint* L = (uint*)(Xlo + (size_t)p0 * CC);
        for (int e = t; e < 64 * CC / 2; e += 256) { H[e] = 0u; L[e] = 0u; }
        return;
    }

    __shared__ float xs[CC][65];
    const float* xb = x + ((size_t)n * CC) * (HH * WW) + (size_t)gh * WW + wcol;
    for (int e = t; e < CC * 16; e += 256) {
        int ic = e >> 4, j = e & 15;
        float4 v = *(const float4*)(xb + (size_t)ic * (HH * WW) + j * 4);
        xs[ic][j * 4 + 0] = v.x;
        xs[ic][j * 4 + 1] = v.y;
        xs[ic][j * 4 + 2] = v.z;
        xs[ic][j * 4 + 3] = v.w;
    }
    __syncthreads();

    const int r = t >> 2;            // local position 0..63
    const int k0 = (t & 3) * 48;     // k-chunk
    size_t orow = ((size_t)p0 + r) * CC + k0;
    uint* H = (uint*)(Xhi + orow);
    uint* L = (uint*)(Xlo + orow);
    #pragma unroll
    for (int j = 0; j < 48; j += 2) {
        float va = xs[k0 + j][r], vb = xs[k0 + j + 1][r];
        ushort ha = f2b(va), hb = f2b(vb);
        ushort la = f2b(va - b2f(ha)), lb = f2b(vb - b2f(hb));
        H[j >> 1] = (uint)ha | ((uint)hb << 16);
        L[j >> 1] = (uint)la | ((uint)lb << 16);
    }
}

// ---------------------------------------------------------------------------
// gemm_split: C[M][N] = W[M][192] * B[192][N], split-bf16 (hh + hl + lh).
// 1-D grid with XCD-chunked bijective swizzle (NP % 8 == 0 required).
// B element (p, k) at: Bpl + (k>>5)*SS + p*RS + (k&31).
// ---------------------------------------------------------------------------
__global__ __launch_bounds__(256) void gemm_split(const ushort* __restrict__ Whi,
                                                  const ushort* __restrict__ Wlo,
                                                  const ushort* __restrict__ Bhi,
                                                  const ushort* __restrict__ Blo,
                                                  float* __restrict__ C, int ldc,
                                                  int RS, int SS, int NM) {
    __shared__ ushort lA[2][64][64];    // [plane][m][k]  16 KB
    __shared__ ushort lB[2][128][64];   // [plane][p][k]  32 KB

    const int bid = blockIdx.x;
    const int xcd = bid & 7;
    const int idx = bid >> 3;
    const int ptpx = (int)(gridDim.x >> 3) / NM;   // ptiles per XCD
    const int mtile = (idx % NM) * 64;
    const int ptile = (xcd * ptpx + idx / NM) * 128;

    const int t = threadIdx.x, wv = t >> 6, ln = t & 63;
    const int wm = wv >> 1, wn = wv & 1;

    f32x4 zero = {0.f, 0.f, 0.f, 0.f};
    f32x4 acc[2][4];
    #pragma unroll
    for (int fm = 0; fm < 2; ++fm)
        #pragma unroll
        for (int fn = 0; fn < 4; ++fn) acc[fm][fn] = zero;

    const int r8 = ln >> 3, s = ln & 7;

    for (int kk = 0; kk < 3; ++kk) {
        const int k0 = kk * 64;
        #pragma unroll
        for (int ci = 0; ci < 12; ++ci) {
            const int c = wv * 12 + ci;
            const ushort* g;
            void* l;
            if (c < 16) {               // A (weights)
                const int pl = c >> 3, ch = c & 7;
                const int r = ch * 8 + r8;
                g = (pl ? Wlo : Whi) + (size_t)(mtile + r) * CC + k0 + ((s ^ (r & 7)) << 3);
                l = (void*)&lA[pl][ch * 8][0];
            } else {                    // B (activations)
                const int c2 = c - 16;
                const int pl = c2 >> 4, ch = c2 & 15;
                const int r = ch * 8 + r8;
                const int kq = k0 + ((s ^ (r & 7)) << 3);
                g = (pl ? Blo : Bhi) + (size_t)(kq >> 5) * (size_t)SS
                                      + (size_t)(ptile + r) * (size_t)RS + (kq & 31);
                l = (void*)&lB[pl][ch * 8][0];
            }
            gl_lds16(g, l);
        }
        __syncthreads();

        #pragma unroll
        for (int ks = 0; ks < 2; ++ks) {
            bf16x8 ah[2], al[2], bh[4], bl[4];
            #pragma unroll
            for (int fm = 0; fm < 2; ++fm) {
                const int r = wm * 32 + fm * 16 + (ln & 15);
                const int col = (((ks * 4 + (ln >> 4)) ^ (r & 7)) << 3);
                ah[fm] = *(const bf16x8*)&lA[0][r][col];
                al[fm] = *(const bf16x8*)&lA[1][r][col];
            }
            #pragma unroll
            for (int fn = 0; fn < 4; ++fn) {
                const int r = wn * 64 + fn * 16 + (ln & 15);
                const int col = (((ks * 4 + (ln >> 4)) ^ (r & 7)) << 3);
                bh[fn] = *(const bf16x8*)&lB[0][r][col];
                bl[fn] = *(const bf16x8*)&lB[1][r][col];
            }
            #pragma unroll
            for (int fm = 0; fm < 2; ++fm)
                #pragma unroll
                for (int fn = 0; fn < 4; ++fn) {
                    acc[fm][fn] = __builtin_amdgcn_mfma_f32_16x16x32_bf16(ah[fm], bh[fn], acc[fm][fn], 0, 0, 0);
                    acc[fm][fn] = __builtin_amdgcn_mfma_f32_16x16x32_bf16(ah[fm], bl[fn], acc[fm][fn], 0, 0, 0);
                    acc[fm][fn] = __builtin_amdgcn_mfma_f32_16x16x32_bf16(al[fm], bh[fn], acc[fm][fn], 0, 0, 0);
                }
        }
        __syncthreads();
    }

    #pragma unroll
    for (int fm = 0; fm < 2; ++fm)
        #pragma unroll
        for (int fn = 0; fn < 4; ++fn)
            #pragma unroll
            for (int r = 0; r < 4; ++r) {
                const int m = mtile + wm * 32 + fm * 16 + (ln >> 4) * 4 + r;
                const int p = ptile + wn * 64 + fn * 16 + (ln & 15);
                C[(size_t)m * ldc + p] = acc[fm][fn][r];
            }
}

// ---------------------------------------------------------------------------
// K2 v2: register-rolling fused dw3x3(w2) -> dw3x3(w3).  No LDS.
// One 64-lane wave = one (channel, 32-row strip); lane owns a float4 w-chunk
// (wave covers the full 256-wide row; w-halos via shfl, zeroed at edges).
// Rolls down h with 3 input rows + 3 mid rows in registers.
// mid is forced to 0 at global rows/cols outside the image (the second conv
// pads the FIRST conv's output).
// ---------------------------------------------------------------------------
struct RowH { float4 v; float l, r; };

__device__ __forceinline__ RowH k2_load(const float* p, int ln) {
    RowH q;
    q.v = *(const float4*)p;
    q.l = __shfl_up(q.v.w, 1);
    q.r = __shfl_down(q.v.x, 1);
    if (ln == 0) q.l = 0.f;
    if (ln == 63) q.r = 0.f;
    return q;
}

__device__ __forceinline__ float4 k2_conv(const RowH& a, const RowH& b, const RowH& c,
                                          const float* w) {
    float4 o;
    o.x = fmaf(a.l,   w[0], fmaf(a.v.x, w[1], fmaf(a.v.y, w[2],
          fmaf(b.l,   w[3], fmaf(b.v.x, w[4], fmaf(b.v.y, w[5],
          fmaf(c.l,   w[6], fmaf(c.v.x, w[7], c.v.y * w[8]))))))));
    o.y = fmaf(a.v.x, w[0], fmaf(a.v.y, w[1], fmaf(a.v.z, w[2],
          fmaf(b.v.x, w[3], fmaf(b.v.y, w[4], fmaf(b.v.z, w[5],
          fmaf(c.v.x, w[6], fmaf(c.v.y, w[7], c.v.z * w[8]))))))));
    o.z = fmaf(a.v.y, w[0], fmaf(a.v.z, w[1], fmaf(a.v.w, w[2],
          fmaf(b.v.y, w[3], fmaf(b.v.z, w[4], fmaf(b.v.w, w[5],
          fmaf(c.v.y, w[6], fmaf(c.v.z, w[7], c.v.w * w[8]))))))));
    o.w = fmaf(a.v.z, w[0], fmaf(a.v.w, w[1], fmaf(a.r,   w[2],
          fmaf(b.v.z, w[3], fmaf(b.v.w, w[4], fmaf(b.r,   w[5],
          fmaf(c.v.z, w[6], fmaf(c.v.w, w[7], c.r * w[8]))))))));
    return o;
}

__device__ __forceinline__ RowH k2_mid(const RowH& a, const RowH& b, const RowH& c,
                                       const float* w, bool zero, int ln) {
    RowH m;
    if (zero) {                 // wave-uniform
        m.v = make_float4(0.f, 0.f, 0.f, 0.f);
        m.l = 0.f; m.r = 0.f;
        return m;
    }
    m.v = k2_conv(a, b, c, w);
    m.l = __shfl_up(m.v.w, 1);
    m.r = __shfl_down(m.v.x, 1);
    if (ln == 0) m.l = 0.f;
    if (ln == 63) m.r = 0.f;
    return m;
}

__global__ __launch_bounds__(256) void k2_dwdw(const float* __restrict__ A,
                                               const float* __restrict__ w2,
                                               const float* __restrict__ w3,
                                               float* __restrict__ B,
                                               int h0, int BH, int strips) {
    const int SR = BH / strips;                  // 32
    const int wv = threadIdx.x >> 6, ln = threadIdx.x & 63;
    const int gid = blockIdx.x * 4 + wv;
    const int c = gid / strips;
    const int s = gid - c * strips;
    const int r0 = s * SR;

    float w2c[9], w3c[9];
    #pragma unroll
    for (int i = 0; i < 9; ++i) { w2c[i] = w2[c * 9 + i]; w3c[i] = w3[c * 9 + i]; }

    const float* Ac = A + (size_t)c * (BH + 4) * WW + 4 * ln;
    float* Bc = B + (size_t)c * BH * WW + 4 * ln;

    // prologue: mid[r0-1], mid[r0]   (mid[r'] needs A rows r'+1..r'+3)
    RowH i0 = k2_load(Ac + (size_t)(r0 + 0) * WW, ln);
    RowH i1 = k2_load(Ac + (size_t)(r0 + 1) * WW, ln);
    RowH i2 = k2_load(Ac + (size_t)(r0 + 2) * WW, ln);
    RowH m0 = k2_mid(i0, i1, i2, w2c, (h0 + r0 - 1) < 0, ln);
    i0 = i1; i1 = i2;
    i2 = k2_load(Ac + (size_t)(r0 + 3) * WW, ln);
    RowH m1 = k2_mid(i0, i1, i2, w2c, false, ln);

    #pragma unroll 4
    for (int r = r0; r < r0 + SR; ++r) {
        i0 = i1; i1 = i2;
        i2 = k2_load(Ac + (size_t)(r + 4) * WW, ln);
        RowH m2 = k2_mid(i0, i1, i2, w2c, (h0 + r + 1) >= HH, ln);
        float4 o = k2_conv(m0, m1, m2, w3c);
        *(float4*)(Bc + (size_t)r * WW) = o;
        m0 = m1; m1 = m2;
    }
}

// ---------------------------------------------------------------------------
// K3 (MFMA): row-wise attention, 64 KB LDS -> 2 blocks/CU.
// ---------------------------------------------------------------------------
__global__ __launch_bounds__(512, 4) void k3_attn_mfma(const float* __restrict__ Bq,
                                                       const float* __restrict__ factor,
                                                       ushort* __restrict__ Ohi,
                                                       ushort* __restrict__ Olo, int BH) {
    const int r = blockIdx.x / NHD;
    const int head = blockIdx.x % NHD;
    const int t = threadIdx.x;
    const size_t plane = (size_t)BH * WW;

    __shared__ __align__(16) char arena[65536];
    ushort* Ksp = (ushort*)arena;            // [2][256 key][32 d], hi @0, lo @8192 (ushort idx)
    ushort* Vt  = (ushort*)(arena + 32768);  // [2][32 d][256 key'] permuted+swizzled
    uint*   Oar = (uint*)arena;              // [2][256][20] epilogue alias (40 KB)

    if (t < 256) {
        // ---- stage K row t: load, normalize, split, swizzled store ----
        const int row = t;
        const float* base = Bq + ((size_t)(CC + head * DH)) * plane + (size_t)r * WW + row;
        float v[32];
        #pragma unroll
        for (int d = 0; d < 32; ++d) v[d] = base[(size_t)d * plane];
        float ss = 0.f;
        #pragma unroll
        for (int d = 0; d < 32; ++d) ss = fmaf(v[d], v[d], ss);
        const float inv = 1.f / fmaxf(sqrtf(ss), 1e-12f);
        const int sw = (row >> 1) & 3;
        #pragma unroll
        for (int d = 0; d < 32; d += 2) {
            float v0 = v[d] * inv, v1 = v[d + 1] * inv;
            ushort h0 = f2b(v0), h1 = f2b(v1);
            ushort g0 = f2b(v0 - b2f(h0)), g1 = f2b(v1 - b2f(h1));
            int dd = (d & 7) | ((((d >> 3) ^ sw) & 3) << 3);
            *(uint*)&Ksp[row * 32 + dd] = (uint)h0 | ((uint)h1 << 16);
            *(uint*)&Ksp[8192 + row * 32 + dd] = (uint)g0 | ((uint)g1 << 16);
        }
    } else {
        // ---- stage V column k (permuted key' = 32s|8g|4b|rr) ----
        const int k = t - 256;
        const int kp = (k & 0xE3) | (((k >> 2) & 3) << 3) | (((k >> 4) & 1) << 2);
        const float* base = Bq + ((size_t)(2 * CC + head * DH)) * plane + (size_t)r * WW + k;
        const int slot = kp >> 3, inb = kp & 7;
        #pragma unroll
        for (int d = 0; d < 32; ++d) {
            float val = base[(size_t)d * plane];
            ushort h = f2b(val);
            ushort g = f2b(val - b2f(h));
            int col = ((slot ^ (d & 7)) << 3) | inb;
            Vt[d * 256 + col] = h;
            Vt[8192 + d * 256 + col] = g;
        }
    }
    __syncthreads();

    const int wv = t >> 6, ln = t & 63;
    const int hig = ln >> 4, lo16 = ln & 15;
    const float fsc = factor[0];

    f32x4 osave[2][2];
    float invl[2];

    #pragma unroll
    for (int c = 0; c < 2; ++c) {
        const int qrow = wv * 32 + c * 16 + lo16;

        // ---- q fragment from global; cooperative norm via shfl ----
        float qv[8];
        {
            const float* qb = Bq + ((size_t)(head * DH + hig * 8)) * plane + (size_t)r * WW + qrow;
            #pragma unroll
            for (int j = 0; j < 8; ++j) qv[j] = qb[(size_t)j * plane];
        }
        float ssq = 0.f;
        #pragma unroll
        for (int j = 0; j < 8; ++j) ssq = fmaf(qv[j], qv[j], ssq);
        ssq += __shfl_xor(ssq, 16);
        ssq += __shfl_xor(ssq, 32);
        const float qinv = fsc / fmaxf(sqrtf(ssq), 1e-12f);
        union { bf16x8 v; uint u[4]; } qh, qlo;
        #pragma unroll
        for (int j = 0; j < 8; j += 2) {
            float v0 = qv[j] * qinv, v1 = qv[j + 1] * qinv;
            ushort h0 = f2b(v0), h1 = f2b(v1);
            ushort g0 = f2b(v0 - b2f(h0)), g1 = f2b(v1 - b2f(h1));
            qh.u[j >> 1] = (uint)h0 | ((uint)h1 << 16);
            qlo.u[j >> 1] = (uint)g0 | ((uint)g1 << 16);
        }

        // ---- S^T: 16 key-frags, split products hh+hl+lh ----
        f32x4 s[16];
        __builtin_amdgcn_s_setprio(1);
        #pragma unroll
        for (int f = 0; f < 16; ++f) {
            const int krow = f * 16 + lo16;
            const int koff = krow * 32 + ((hig ^ ((krow >> 1) & 3)) << 3);
            const bf16x8 kh = *(const bf16x8*)&Ksp[koff];
            const bf16x8 klo = *(const bf16x8*)&Ksp[8192 + koff];
            f32x4 a = {0.f, 0.f, 0.f, 0.f};
            a = __builtin_amdgcn_mfma_f32_16x16x32_bf16(kh, qh.v, a, 0, 0, 0);
            a = __builtin_amdgcn_mfma_f32_16x16x32_bf16(kh, qlo.v, a, 0, 0, 0);
            a = __builtin_amdgcn_mfma_f32_16x16x32_bf16(klo, qh.v, a, 0, 0, 0);
            s[f] = a;
        }
        __builtin_amdgcn_s_setprio(0);

        // ---- softmax (lane holds full row for q = lane&15) ----
        float mx = -3.0e38f;
        #pragma unroll
        for (int f = 0; f < 16; ++f)
            mx = fmaxf(mx, fmaxf(fmaxf(s[f][0], s[f][1]), fmaxf(s[f][2], s[f][3])));
        mx = fmaxf(mx, __shfl_xor(mx, 16));
        mx = fmaxf(mx, __shfl_xor(mx, 32));
        float lsum = 0.f;
        #pragma unroll
        for (int f = 0; f < 16; ++f) {
            #pragma unroll
            for (int rr = 0; rr < 4; ++rr) {
                float p = __expf(s[f][rr] - mx);
                s[f][rr] = p;
                lsum += p;
            }
        }
        lsum += __shfl_xor(lsum, 16);
        lsum += __shfl_xor(lsum, 32);
        invl[c] = 1.f / lsum;

        // ---- pack P to split bf16 (local pairs along regs) ----
        uint phh[16][2], pll[16][2];
        #pragma unroll
        for (int f = 0; f < 16; ++f) {
            ushort h0 = f2b(s[f][0]), h1 = f2b(s[f][1]), h2 = f2b(s[f][2]), h3 = f2b(s[f][3]);
            phh[f][0] = (uint)h0 | ((uint)h1 << 16);
            phh[f][1] = (uint)h2 | ((uint)h3 << 16);
            ushort g0 = f2b(s[f][0] - b2f(h0)), g1 = f2b(s[f][1] - b2f(h1));
            ushort g2 = f2b(s[f][2] - b2f(h2)), g3 = f2b(s[f][3] - b2f(h3));
            pll[f][0] = (uint)g0 | ((uint)g1 << 16);
            pll[f][1] = (uint)g2 | ((uint)g3 << 16);
        }

        // ---- PV over permuted key order: out^T = V^T x P^T ----
        f32x4 o0a = {0,0,0,0}, o0b = {0,0,0,0}, o1a = {0,0,0,0}, o1b = {0,0,0,0};
        __builtin_amdgcn_s_setprio(1);
        #pragma unroll
        for (int st = 0; st < 8; ++st) {
            union { bf16x8 v; uint u[4]; } pbh, pbl;
            pbh.u[0] = phh[2*st][0];   pbh.u[1] = phh[2*st][1];
            pbh.u[2] = phh[2*st+1][0]; pbh.u[3] = phh[2*st+1][1];
            pbl.u[0] = pll[2*st][0];   pbl.u[1] = pll[2*st][1];
            pbl.u[2] = pll[2*st+1][0]; pbl.u[3] = pll[2*st+1][1];
            {
                const int drow = lo16;
                const int voff = drow * 256 + (((4*st + hig) ^ (drow & 7)) << 3);
                const bf16x8 vh = *(const bf16x8*)&Vt[voff];
                const bf16x8 vl = *(const bf16x8*)&Vt[8192 + voff];
                f32x4& o = (st & 1) ? o0b : o0a;
                o = __builtin_amdgcn_mfma_f32_16x16x32_bf16(vh, pbh.v, o, 0, 0, 0);
                o = __builtin_amdgcn_mfma_f32_16x16x32_bf16(vh, pbl.v, o, 0, 0, 0);
                o = __builtin_amdgcn_mfma_f32_16x16x32_bf16(vl, pbh.v, o, 0, 0, 0);
            }
            {
                const int drow = 16 + lo16;
                const int voff = drow * 256 + (((4*st + hig) ^ (drow & 7)) << 3);
                const bf16x8 vh = *(const bf16x8*)&Vt[voff];
                const bf16x8 vl = *(const bf16x8*)&Vt[8192 + voff];
                f32x4& o = (st & 1) ? o1b : o1a;
                o = __builtin_amdgcn_mfma_f32_16x16x32_bf16(vh, pbh.v, o, 0, 0, 0);
                o = __builtin_amdgcn_mfma_f32_16x16x32_bf16(vh, pbl.v, o, 0, 0, 0);
                o = __builtin_amdgcn_mfma_f32_16x16x32_bf16(vl, pbh.v, o, 0, 0, 0);
            }
        }
        __builtin_amdgcn_s_setprio(0);
        #pragma unroll
        for (int rr = 0; rr < 4; ++rr) { o0a[rr] += o0b[rr]; o1a[rr] += o1b[rr]; }
        osave[c][0] = o0a;
        osave[c][1] = o1a;
    }

    __syncthreads();   // all waves done reading Ksp/Vt before Oar overwrite

    // ---- scale + split + transpose through LDS ----
    #pragma unroll
    for (int c = 0; c < 2; ++c) {
        const int qrow = wv * 32 + c * 16 + lo16;
        #pragma unroll
        for (int fm = 0; fm < 2; ++fm) {
            const f32x4 o = osave[c][fm];
            const float s0 = o[0] * invl[c], s1 = o[1] * invl[c];
            const float s2 = o[2] * invl[c], s3 = o[3] * invl[c];
            const ushort h0 = f2b(s0), h1 = f2b(s1), h2 = f2b(s2), h3 = f2b(s3);
            const ushort g0 = f2b(s0 - b2f(h0)), g1 = f2b(s1 - b2f(h1));
            const ushort g2 = f2b(s2 - b2f(h2)), g3 = f2b(s3 - b2f(h3));
            const int dp = 8 * fm + 2 * hig;           // u32 index of d-pair
            Oar[qrow * 20 + dp]            = (uint)h0 | ((uint)h1 << 16);
            Oar[qrow * 20 + dp + 1]        = (uint)h2 | ((uint)h3 << 16);
            Oar[5120 + qrow * 20 + dp]     = (uint)g0 | ((uint)g1 << 16);
            Oar[5120 + qrow * 20 + dp + 1] = (uint)g2 | ((uint)g3 << 16);
        }
    }
    __syncthreads();

    // ---- per-block contiguous writes: O[head][r*256+t][32] split planes ----
    if (t < 256) {
        const size_t obase = ((size_t)head * (size_t)BH * WW + (size_t)r * WW + t) * DH;
        uint4* dh_ = (uint4*)(Ohi + obase);
        uint4* dl_ = (uint4*)(Olo + obase);
        const uint* srcH = &Oar[t * 20];
        const uint* srcL = &Oar[5120 + t * 20];
        #pragma unroll
        for (int i = 0; i < 4; ++i) {
            dh_[i] = *(const uint4*)&srcH[i * 4];
            dl_[i] = *(const uint4*)&srcL[i * 4];
        }
    }
}

extern "C" void kernel_launch(void* const* d_in, const int* in_sizes, int n_in,
                              void* d_out, int out_size, void* d_ws, size_t ws_size,
                              hipStream_t stream) {
    const float* x      = (const float*)d_in[0];
    const float* w1     = (const float*)d_in[1];
    const float* w2     = (const float*)d_in[2];
    const float* w3     = (const float*)d_in[3];
    const float* factor = (const float*)d_in[4];
    const float* wf     = (const float*)d_in[5];
    float* out = (float*)d_out;

    const size_t SW = (size_t)(C3 + CC) * CC * 2 * sizeof(ushort);   // w splits (hi+lo)
    int BH = 256;                       // full image per batch if ws allows (~305 MB)
    while (BH > 32) {
        size_t SA_ = (size_t)C3 * (BH + 4) * WW * 4;
        size_t SB_ = (size_t)C3 * BH * WW * 4;
        if (SA_ + SB_ + SW <= ws_size) break;
        BH >>= 1;
    }
    const size_t SA = (size_t)C3 * (BH + 4) * WW * 4;
    const size_t SB = (size_t)C3 * BH * WW * 4;

    float*  A   = (float*)d_ws;                            // qkv1 region; later O hi/lo
    float*  Bq  = (float*)((char*)d_ws + SA);              // qkv3 region; earlier Xt hi/lo
    ushort* Wsp = (ushort*)((char*)d_ws + SA + SB);        // weight splits
    ushort* Whi = Wsp;                                     // [768][192]
    ushort* Wlo = Wsp + (size_t)(C3 + CC) * CC;

    ushort* Xhi = (ushort*)Bq;                             // [(BH+4)*256][192]
    ushort* Xlo = Xhi + (size_t)(BH + 4) * WW * CC;
    ushort* Ohi = (ushort*)A;                              // [6][BH*256][32]
    ushort* Olo = Ohi + (size_t)NHD * BH * WW * DH;

    prep_w<<<dim3((C3 + CC) * CC / 256), dim3(256), 0, stream>>>(w1, wf, Whi, Wlo);

    for (int n = 0; n < NB; ++n) {
        for (int h0 = 0; h0 < HH; h0 += BH) {
            const int strips = BH / 32;
            prep_xt<<<dim3((BH + 4) * (WW / 64)), dim3(256), 0, stream>>>(x, Xhi, Xlo, n, h0, BH);
            gemm_split<<<dim3(((BH + 4) * WW / 128) * (C3 / 64)), dim3(256), 0, stream>>>(
                Whi, Wlo, Xhi, Xlo, A, (BH + 4) * WW, CC, DH, C3 / 64);
            k2_dwdw<<<dim3(C3 * strips / 4), dim3(256), 0, stream>>>(A, w2, w3, Bq, h0, BH, strips);
            k3_attn_mfma<<<dim3(NHD * BH), dim3(512), 0, stream>>>(Bq, factor, Ohi, Olo, BH);
            gemm_split<<<dim3((BH * WW / 128) * (CC / 64)), dim3(256), 0, stream>>>(
                Whi + (size_t)C3 * CC, Wlo + (size_t)C3 * CC, Ohi, Olo,
                out + ((size_t)n * CC) * HH * WW + (size_t)h0 * WW, HH * WW,
                DH, BH * WW * DH, CC / 64);
        }
    }
}

// Round 8
// 534.679 us; speedup vs baseline: 3.1195x; 1.0121x over previous
//
#include <hip/hip_runtime.h>
#include <hip/hip_bf16.h>
#include <math.h>

#define NB 2
#define CC 192
#define HH 256
#define WW 256
#define NHD 6
#define DH 32
#define C3 576   // 3*CC

typedef __attribute__((ext_vector_type(8))) short bf16x8;
typedef __attribute__((ext_vector_type(4))) float f32x4;

__device__ __forceinline__ ushort f2b(float v) {
    __hip_bfloat16 b = __float2bfloat16(v);
    return *reinterpret_cast<ushort*>(&b);
}
__device__ __forceinline__ float b2f(ushort u) {
    __hip_bfloat16 b;
    *reinterpret_cast<ushort*>(&b) = u;
    return __bfloat162float(b);
}

__device__ __forceinline__ void gl_lds16(const void* g, void* l) {
    __builtin_amdgcn_global_load_lds((const __attribute__((address_space(1))) void*)g,
                                     (__attribute__((address_space(3))) void*)l, 16, 0, 0);
}

// ---------------------------------------------------------------------------
// prep_w: split w1[576x192] and wf[192x192] fp32 -> bf16 hi/lo planes.
// ---------------------------------------------------------------------------
__global__ __launch_bounds__(256) void prep_w(const float* __restrict__ w1,
                                              const float* __restrict__ wf,
                                              ushort* __restrict__ Whi,
                                              ushort* __restrict__ Wlo) {
    int i = blockIdx.x * 256 + threadIdx.x;       // < 147456
    float v = (i < C3 * CC) ? w1[i] : wf[i - C3 * CC];
    ushort h = f2b(v);
    Whi[i] = h;
    Wlo[i] = f2b(v - b2f(h));
}

// ---------------------------------------------------------------------------
// prep_xt: transpose+split band of x -> Xt[p][k] bf16 hi/lo, p = a*256+w.
// ---------------------------------------------------------------------------
__global__ __launch_bounds__(256) void prep_xt(const float* __restrict__ x,
                                               ushort* __restrict__ Xhi,
                                               ushort* __restrict__ Xlo,
                                               int n, int h0, int BH) {
    const int p0 = blockIdx.x * 64;
    const int gh = h0 - 2 + (p0 >> 8);
    const int wcol = p0 & 255;
    const int t = threadIdx.x;

    if (gh < 0 || gh >= HH) {
        uint* H = (uint*)(Xhi + (size_t)p0 * CC);
        uint* L = (uint*)(Xlo + (size_t)p0 * CC);
        for (int e = t; e < 64 * CC / 2; e += 256) { H[e] = 0u; L[e] = 0u; }
        return;
    }

    __shared__ float xs[CC][65];
    const float* xb = x + ((size_t)n * CC) * (HH * WW) + (size_t)gh * WW + wcol;
    for (int e = t; e < CC * 16; e += 256) {
        int ic = e >> 4, j = e & 15;
        float4 v = *(const float4*)(xb + (size_t)ic * (HH * WW) + j * 4);
        xs[ic][j * 4 + 0] = v.x;
        xs[ic][j * 4 + 1] = v.y;
        xs[ic][j * 4 + 2] = v.z;
        xs[ic][j * 4 + 3] = v.w;
    }
    __syncthreads();

    const int r = t >> 2;            // local position 0..63
    const int k0 = (t & 3) * 48;     // k-chunk
    size_t orow = ((size_t)p0 + r) * CC + k0;
    uint* H = (uint*)(Xhi + orow);
    uint* L = (uint*)(Xlo + orow);
    #pragma unroll
    for (int j = 0; j < 48; j += 2) {
        float va = xs[k0 + j][r], vb = xs[k0 + j + 1][r];
        ushort ha = f2b(va), hb = f2b(vb);
        ushort la = f2b(va - b2f(ha)), lb = f2b(vb - b2f(hb));
        H[j >> 1] = (uint)ha | ((uint)hb << 16);
        L[j >> 1] = (uint)la | ((uint)lb << 16);
    }
}

// ---------------------------------------------------------------------------
// gemm_split: C[M][N] = W[M][192] * B[192][N], split-bf16 (hh + hl + lh).
// 1-D grid with XCD-chunked bijective swizzle (NP % 8 == 0 required).
// B element (p, k) at: Bpl + (k>>5)*SS + p*RS + (k&31).
// ---------------------------------------------------------------------------
__global__ __launch_bounds__(256) void gemm_split(const ushort* __restrict__ Whi,
                                                  const ushort* __restrict__ Wlo,
                                                  const ushort* __restrict__ Bhi,
                                                  const ushort* __restrict__ Blo,
                                                  float* __restrict__ C, int ldc,
                                                  int RS, int SS, int NM) {
    __shared__ ushort lA[2][64][64];    // [plane][m][k]  16 KB
    __shared__ ushort lB[2][128][64];   // [plane][p][k]  32 KB

    const int bid = blockIdx.x;
    const int xcd = bid & 7;
    const int idx = bid >> 3;
    const int ptpx = (int)(gridDim.x >> 3) / NM;   // ptiles per XCD
    const int mtile = (idx % NM) * 64;
    const int ptile = (xcd * ptpx + idx / NM) * 128;

    const int t = threadIdx.x, wv = t >> 6, ln = t & 63;
    const int wm = wv >> 1, wn = wv & 1;

    f32x4 zero = {0.f, 0.f, 0.f, 0.f};
    f32x4 acc[2][4];
    #pragma unroll
    for (int fm = 0; fm < 2; ++fm)
        #pragma unroll
        for (int fn = 0; fn < 4; ++fn) acc[fm][fn] = zero;

    const int r8 = ln >> 3, s = ln & 7;

    for (int kk = 0; kk < 3; ++kk) {
        const int k0 = kk * 64;
        #pragma unroll
        for (int ci = 0; ci < 12; ++ci) {
            const int c = wv * 12 + ci;
            const ushort* g;
            void* l;
            if (c < 16) {               // A (weights)
                const int pl = c >> 3, ch = c & 7;
                const int r = ch * 8 + r8;
                g = (pl ? Wlo : Whi) + (size_t)(mtile + r) * CC + k0 + ((s ^ (r & 7)) << 3);
                l = (void*)&lA[pl][ch * 8][0];
            } else {                    // B (activations)
                const int c2 = c - 16;
                const int pl = c2 >> 4, ch = c2 & 15;
                const int r = ch * 8 + r8;
                const int kq = k0 + ((s ^ (r & 7)) << 3);
                g = (pl ? Blo : Bhi) + (size_t)(kq >> 5) * (size_t)SS
                                      + (size_t)(ptile + r) * (size_t)RS + (kq & 31);
                l = (void*)&lB[pl][ch * 8][0];
            }
            gl_lds16(g, l);
        }
        __syncthreads();

        #pragma unroll
        for (int ks = 0; ks < 2; ++ks) {
            bf16x8 ah[2], al[2], bh[4], bl[4];
            #pragma unroll
            for (int fm = 0; fm < 2; ++fm) {
                const int r = wm * 32 + fm * 16 + (ln & 15);
                const int col = (((ks * 4 + (ln >> 4)) ^ (r & 7)) << 3);
                ah[fm] = *(const bf16x8*)&lA[0][r][col];
                al[fm] = *(const bf16x8*)&lA[1][r][col];
            }
            #pragma unroll
            for (int fn = 0; fn < 4; ++fn) {
                const int r = wn * 64 + fn * 16 + (ln & 15);
                const int col = (((ks * 4 + (ln >> 4)) ^ (r & 7)) << 3);
                bh[fn] = *(const bf16x8*)&lB[0][r][col];
                bl[fn] = *(const bf16x8*)&lB[1][r][col];
            }
            #pragma unroll
            for (int fm = 0; fm < 2; ++fm)
                #pragma unroll
                for (int fn = 0; fn < 4; ++fn) {
                    acc[fm][fn] = __builtin_amdgcn_mfma_f32_16x16x32_bf16(ah[fm], bh[fn], acc[fm][fn], 0, 0, 0);
                    acc[fm][fn] = __builtin_amdgcn_mfma_f32_16x16x32_bf16(ah[fm], bl[fn], acc[fm][fn], 0, 0, 0);
                    acc[fm][fn] = __builtin_amdgcn_mfma_f32_16x16x32_bf16(al[fm], bh[fn], acc[fm][fn], 0, 0, 0);
                }
        }
        __syncthreads();
    }

    #pragma unroll
    for (int fm = 0; fm < 2; ++fm)
        #pragma unroll
        for (int fn = 0; fn < 4; ++fn)
            #pragma unroll
            for (int r = 0; r < 4; ++r) {
                const int m = mtile + wm * 32 + fm * 16 + (ln >> 4) * 4 + r;
                const int p = ptile + wn * 64 + fn * 16 + (ln & 15);
                C[(size_t)m * ldc + p] = acc[fm][fn][r];
            }
}

// ---------------------------------------------------------------------------
// K2: register-rolling fused dw3x3(w2) -> dw3x3(w3).  No LDS.
// ---------------------------------------------------------------------------
struct RowH { float4 v; float l, r; };

__device__ __forceinline__ RowH k2_load(const float* p, int ln) {
    RowH q;
    q.v = *(const float4*)p;
    q.l = __shfl_up(q.v.w, 1);
    q.r = __shfl_down(q.v.x, 1);
    if (ln == 0) q.l = 0.f;
    if (ln == 63) q.r = 0.f;
    return q;
}

__device__ __forceinline__ float4 k2_conv(const RowH& a, const RowH& b, const RowH& c,
                                          const float* w) {
    float4 o;
    o.x = fmaf(a.l,   w[0], fmaf(a.v.x, w[1], fmaf(a.v.y, w[2],
          fmaf(b.l,   w[3], fmaf(b.v.x, w[4], fmaf(b.v.y, w[5],
          fmaf(c.l,   w[6], fmaf(c.v.x, w[7], c.v.y * w[8]))))))));
    o.y = fmaf(a.v.x, w[0], fmaf(a.v.y, w[1], fmaf(a.v.z, w[2],
          fmaf(b.v.x, w[3], fmaf(b.v.y, w[4], fmaf(b.v.z, w[5],
          fmaf(c.v.x, w[6], fmaf(c.v.y, w[7], c.v.z * w[8]))))))));
    o.z = fmaf(a.v.y, w[0], fmaf(a.v.z, w[1], fmaf(a.v.w, w[2],
          fmaf(b.v.y, w[3], fmaf(b.v.z, w[4], fmaf(b.v.w, w[5],
          fmaf(c.v.y, w[6], fmaf(c.v.z, w[7], c.v.w * w[8]))))))));
    o.w = fmaf(a.v.z, w[0], fmaf(a.v.w, w[1], fmaf(a.r,   w[2],
          fmaf(b.v.z, w[3], fmaf(b.v.w, w[4], fmaf(b.r,   w[5],
          fmaf(c.v.z, w[6], fmaf(c.v.w, w[7], c.r * w[8]))))))));
    return o;
}

__device__ __forceinline__ RowH k2_mid(const RowH& a, const RowH& b, const RowH& c,
                                       const float* w, bool zero, int ln) {
    RowH m;
    if (zero) {                 // wave-uniform
        m.v = make_float4(0.f, 0.f, 0.f, 0.f);
        m.l = 0.f; m.r = 0.f;
        return m;
    }
    m.v = k2_conv(a, b, c, w);
    m.l = __shfl_up(m.v.w, 1);
    m.r = __shfl_down(m.v.x, 1);
    if (ln == 0) m.l = 0.f;
    if (ln == 63) m.r = 0.f;
    return m;
}

__global__ __launch_bounds__(256) void k2_dwdw(const float* __restrict__ A,
                                               const float* __restrict__ w2,
                                               const float* __restrict__ w3,
                                               float* __restrict__ B,
                                               int h0, int BH, int strips) {
    const int SR = BH / strips;                  // 32
    const int wv = threadIdx.x >> 6, ln = threadIdx.x & 63;
    const int gid = blockIdx.x * 4 + wv;
    const int c = gid / strips;
    const int s = gid - c * strips;
    const int r0 = s * SR;

    float w2c[9], w3c[9];
    #pragma unroll
    for (int i = 0; i < 9; ++i) { w2c[i] = w2[c * 9 + i]; w3c[i] = w3[c * 9 + i]; }

    const float* Ac = A + (size_t)c * (BH + 4) * WW + 4 * ln;
    float* Bc = B + (size_t)c * BH * WW + 4 * ln;

    // prologue: mid[r0-1], mid[r0]   (mid[r'] needs A rows r'+1..r'+3)
    RowH i0 = k2_load(Ac + (size_t)(r0 + 0) * WW, ln);
    RowH i1 = k2_load(Ac + (size_t)(r0 + 1) * WW, ln);
    RowH i2 = k2_load(Ac + (size_t)(r0 + 2) * WW, ln);
    RowH m0 = k2_mid(i0, i1, i2, w2c, (h0 + r0 - 1) < 0, ln);
    i0 = i1; i1 = i2;
    i2 = k2_load(Ac + (size_t)(r0 + 3) * WW, ln);
    RowH m1 = k2_mid(i0, i1, i2, w2c, false, ln);

    #pragma unroll 4
    for (int r = r0; r < r0 + SR; ++r) {
        i0 = i1; i1 = i2;
        i2 = k2_load(Ac + (size_t)(r + 4) * WW, ln);
        RowH m2 = k2_mid(i0, i1, i2, w2c, (h0 + r + 1) >= HH, ln);
        float4 o = k2_conv(m0, m1, m2, w3c);
        *(float4*)(Bc + (size_t)r * WW) = o;
        m0 = m1; m1 = m2;
    }
}

// ---------------------------------------------------------------------------
// K3 (MFMA): row-wise attention, 64 KB LDS -> 2 blocks/CU.
// Staging uses WIDE LDS writes (uint4 granules for K, uint2 quads for V via
// the kp-permutation property that 4 consecutive k -> 4 consecutive kp).
// Softmax subtracts the constant |factor| (exact shift-invariance; |S| <=
// |factor| since q,k are L2-normalized) -- no max reduction needed.
// ---------------------------------------------------------------------------
__global__ __launch_bounds__(512, 4) void k3_attn_mfma(const float* __restrict__ Bq,
                                                       const float* __restrict__ factor,
                                                       ushort* __restrict__ Ohi,
                                                       ushort* __restrict__ Olo, int BH) {
    const int r = blockIdx.x / NHD;
    const int head = blockIdx.x % NHD;
    const int t = threadIdx.x;
    const size_t plane = (size_t)BH * WW;

    __shared__ __align__(16) char arena[65536];
    ushort* Ksp = (ushort*)arena;            // [2][256 key][32 d], hi @0, lo @8192 (ushort idx)
    ushort* Vt  = (ushort*)(arena + 32768);  // [2][32 d][256 key'] permuted+swizzled
    uint*   Oar = (uint*)arena;              // [2][256][20] epilogue alias (40 KB)

    if (t < 256) {
        // ---- stage K row t: load, normalize, split, granule-wide stores ----
        const int row = t;
        const float* base = Bq + ((size_t)(CC + head * DH)) * plane + (size_t)r * WW + row;
        float v[32];
        #pragma unroll
        for (int d = 0; d < 32; ++d) v[d] = base[(size_t)d * plane];
        float ss = 0.f;
        #pragma unroll
        for (int d = 0; d < 32; ++d) ss = fmaf(v[d], v[d], ss);
        const float inv = 1.f / fmaxf(sqrtf(ss), 1e-12f);
        const int sw = (row >> 1) & 3;
        #pragma unroll
        for (int gq = 0; gq < 4; ++gq) {
            uint hu[4], lu[4];
            #pragma unroll
            for (int j = 0; j < 4; ++j) {
                float v0 = v[gq * 8 + 2 * j] * inv, v1 = v[gq * 8 + 2 * j + 1] * inv;
                ushort h0 = f2b(v0), h1 = f2b(v1);
                ushort l0 = f2b(v0 - b2f(h0)), l1 = f2b(v1 - b2f(h1));
                hu[j] = (uint)h0 | ((uint)h1 << 16);
                lu[j] = (uint)l0 | ((uint)l1 << 16);
            }
            const int off = row * 32 + ((gq ^ sw) << 3);
            *(uint4*)&Ksp[off] = make_uint4(hu[0], hu[1], hu[2], hu[3]);
            *(uint4*)&Ksp[8192 + off] = make_uint4(lu[0], lu[1], lu[2], lu[3]);
        }
    } else {
        // ---- stage V: thread = (group of 4 consecutive keys, 8 d's).
        // kp = 32s|8g|4b|rr -> 4 consecutive k map to 4 consecutive kp. ----
        const int t2 = t - 256;
        const int kg = t2 & 63;           // k_base = 4*kg
        const int d0 = (t2 >> 6) * 8;
        const int s_ = kg >> 3, b_ = (kg >> 2) & 1, g_ = kg & 3;
        const int kp4 = 32 * s_ + 8 * g_ + 4 * b_;   // multiple of 4
        const int slot = kp4 >> 3, inb = kp4 & 7;
        const float* base = Bq + ((size_t)(2 * CC + head * DH + d0)) * plane
                               + (size_t)r * WW + 4 * kg;
        #pragma unroll
        for (int jd = 0; jd < 8; ++jd) {
            const int d = d0 + jd;
            float4 vv = *(const float4*)(base + (size_t)jd * plane);
            ushort h0 = f2b(vv.x), h1 = f2b(vv.y), h2 = f2b(vv.z), h3 = f2b(vv.w);
            ushort l0 = f2b(vv.x - b2f(h0)), l1 = f2b(vv.y - b2f(h1));
            ushort l2 = f2b(vv.z - b2f(h2)), l3 = f2b(vv.w - b2f(h3));
            const int col = ((slot ^ (d & 7)) << 3) | inb;
            *(uint2*)&Vt[d * 256 + col] =
                make_uint2((uint)h0 | ((uint)h1 << 16), (uint)h2 | ((uint)h3 << 16));
            *(uint2*)&Vt[8192 + d * 256 + col] =
                make_uint2((uint)l0 | ((uint)l1 << 16), (uint)l2 | ((uint)l3 << 16));
        }
    }
    __syncthreads();

    const int wv = t >> 6, ln = t & 63;
    const int hig = ln >> 4, lo16 = ln & 15;
    const float fsc = factor[0];
    const float mb = fabsf(fsc);          // upper bound of |S|; exact softmax shift

    // ---- hoisted q fragments for both chunks: load, coop-norm, split ----
    union { bf16x8 v; uint u[4]; } qh_[2], ql_[2];
    #pragma unroll
    for (int c = 0; c < 2; ++c) {
        const int qrow = wv * 32 + c * 16 + lo16;
        float qv[8];
        const float* qb = Bq + ((size_t)(head * DH + hig * 8)) * plane + (size_t)r * WW + qrow;
        #pragma unroll
        for (int j = 0; j < 8; ++j) qv[j] = qb[(size_t)j * plane];
        float ssq = 0.f;
        #pragma unroll
        for (int j = 0; j < 8; ++j) ssq = fmaf(qv[j], qv[j], ssq);
        ssq += __shfl_xor(ssq, 16);
        ssq += __shfl_xor(ssq, 32);
        const float qinv = fsc / fmaxf(sqrtf(ssq), 1e-12f);
        #pragma unroll
        for (int j = 0; j < 8; j += 2) {
            float v0 = qv[j] * qinv, v1 = qv[j + 1] * qinv;
            ushort h0 = f2b(v0), h1 = f2b(v1);
            ushort g0 = f2b(v0 - b2f(h0)), g1 = f2b(v1 - b2f(h1));
            qh_[c].u[j >> 1] = (uint)h0 | ((uint)h1 << 16);
            ql_[c].u[j >> 1] = (uint)g0 | ((uint)g1 << 16);
        }
    }

    f32x4 osave[2][2];
    float invl[2];

    #pragma unroll
    for (int c = 0; c < 2; ++c) {
        // ---- S^T: 16 key-frags, split products hh+hl+lh ----
        f32x4 s[16];
        __builtin_amdgcn_s_setprio(1);
        #pragma unroll
        for (int f = 0; f < 16; ++f) {
            const int krow = f * 16 + lo16;
            const int koff = krow * 32 + ((hig ^ ((krow >> 1) & 3)) << 3);
            const bf16x8 kh = *(const bf16x8*)&Ksp[koff];
            const bf16x8 klo = *(const bf16x8*)&Ksp[8192 + koff];
            f32x4 a = {0.f, 0.f, 0.f, 0.f};
            a = __builtin_amdgcn_mfma_f32_16x16x32_bf16(kh, qh_[c].v, a, 0, 0, 0);
            a = __builtin_amdgcn_mfma_f32_16x16x32_bf16(kh, ql_[c].v, a, 0, 0, 0);
            a = __builtin_amdgcn_mfma_f32_16x16x32_bf16(klo, qh_[c].v, a, 0, 0, 0);
            s[f] = a;
        }
        __builtin_amdgcn_s_setprio(0);

        // ---- softmax with constant shift (no max reduction) ----
        float lsum = 0.f;
        #pragma unroll
        for (int f = 0; f < 16; ++f) {
            #pragma unroll
            for (int rr = 0; rr < 4; ++rr) {
                float p = __expf(s[f][rr] - mb);
                s[f][rr] = p;
                lsum += p;
            }
        }
        lsum += __shfl_xor(lsum, 16);
        lsum += __shfl_xor(lsum, 32);
        invl[c] = 1.f / lsum;

        // ---- pack P to split bf16 (local pairs along regs) ----
        uint phh[16][2], pll[16][2];
        #pragma unroll
        for (int f = 0; f < 16; ++f) {
            ushort h0 = f2b(s[f][0]), h1 = f2b(s[f][1]), h2 = f2b(s[f][2]), h3 = f2b(s[f][3]);
            phh[f][0] = (uint)h0 | ((uint)h1 << 16);
            phh[f][1] = (uint)h2 | ((uint)h3 << 16);
            ushort g0 = f2b(s[f][0] - b2f(h0)), g1 = f2b(s[f][1] - b2f(h1));
            ushort g2 = f2b(s[f][2] - b2f(h2)), g3 = f2b(s[f][3] - b2f(h3));
            pll[f][0] = (uint)g0 | ((uint)g1 << 16);
            pll[f][1] = (uint)g2 | ((uint)g3 << 16);
        }

        // ---- PV over permuted key order: out^T = V^T x P^T ----
        f32x4 o0a = {0,0,0,0}, o0b = {0,0,0,0}, o1a = {0,0,0,0}, o1b = {0,0,0,0};
        __builtin_amdgcn_s_setprio(1);
        #pragma unroll
        for (int st = 0; st < 8; ++st) {
            union { bf16x8 v; uint u[4]; } pbh, pbl;
            pbh.u[0] = phh[2*st][0];   pbh.u[1] = phh[2*st][1];
            pbh.u[2] = phh[2*st+1][0]; pbh.u[3] = phh[2*st+1][1];
            pbl.u[0] = pll[2*st][0];   pbl.u[1] = pll[2*st][1];
            pbl.u[2] = pll[2*st+1][0]; pbl.u[3] = pll[2*st+1][1];
            {
                const int drow = lo16;
                const int voff = drow * 256 + (((4*st + hig) ^ (drow & 7)) << 3);
                const bf16x8 vh = *(const bf16x8*)&Vt[voff];
                const bf16x8 vl = *(const bf16x8*)&Vt[8192 + voff];
                f32x4& o = (st & 1) ? o0b : o0a;
                o = __builtin_amdgcn_mfma_f32_16x16x32_bf16(vh, pbh.v, o, 0, 0, 0);
                o = __builtin_amdgcn_mfma_f32_16x16x32_bf16(vh, pbl.v, o, 0, 0, 0);
                o = __builtin_amdgcn_mfma_f32_16x16x32_bf16(vl, pbh.v, o, 0, 0, 0);
            }
            {
                const int drow = 16 + lo16;
                const int voff = drow * 256 + (((4*st + hig) ^ (drow & 7)) << 3);
                const bf16x8 vh = *(const bf16x8*)&Vt[voff];
                const bf16x8 vl = *(const bf16x8*)&Vt[8192 + voff];
                f32x4& o = (st & 1) ? o1b : o1a;
                o = __builtin_amdgcn_mfma_f32_16x16x32_bf16(vh, pbh.v, o, 0, 0, 0);
                o = __builtin_amdgcn_mfma_f32_16x16x32_bf16(vh, pbl.v, o, 0, 0, 0);
                o = __builtin_amdgcn_mfma_f32_16x16x32_bf16(vl, pbh.v, o, 0, 0, 0);
            }
        }
        __builtin_amdgcn_s_setprio(0);
        #pragma unroll
        for (int rr = 0; rr < 4; ++rr) { o0a[rr] += o0b[rr]; o1a[rr] += o1b[rr]; }
        osave[c][0] = o0a;
        osave[c][1] = o1a;
    }

    __syncthreads();   // all waves done reading Ksp/Vt before Oar overwrite

    // ---- scale + split + transpose through LDS ----
    #pragma unroll
    for (int c = 0; c < 2; ++c) {
        const int qrow = wv * 32 + c * 16 + lo16;
        #pragma unroll
        for (int fm = 0; fm < 2; ++fm) {
            const f32x4 o = osave[c][fm];
            const float s0 = o[0] * invl[c], s1 = o[1] * invl[c];
            const float s2 = o[2] * invl[c], s3 = o[3] * invl[c];
            const ushort h0 = f2b(s0), h1 = f2b(s1), h2 = f2b(s2), h3 = f2b(s3);
            const ushort g0 = f2b(s0 - b2f(h0)), g1 = f2b(s1 - b2f(h1));
            const ushort g2 = f2b(s2 - b2f(h2)), g3 = f2b(s3 - b2f(h3));
            const int dp = 8 * fm + 2 * hig;           // u32 index of d-pair
            Oar[qrow * 20 + dp]            = (uint)h0 | ((uint)h1 << 16);
            Oar[qrow * 20 + dp + 1]        = (uint)h2 | ((uint)h3 << 16);
            Oar[5120 + qrow * 20 + dp]     = (uint)g0 | ((uint)g1 << 16);
            Oar[5120 + qrow * 20 + dp + 1] = (uint)g2 | ((uint)g3 << 16);
        }
    }
    __syncthreads();

    // ---- per-block contiguous writes: O[head][r*256+t][32] split planes ----
    if (t < 256) {
        const size_t obase = ((size_t)head * (size_t)BH * WW + (size_t)r * WW + t) * DH;
        uint4* dh_ = (uint4*)(Ohi + obase);
        uint4* dl_ = (uint4*)(Olo + obase);
        const uint* srcH = &Oar[t * 20];
        const uint* srcL = &Oar[5120 + t * 20];
        #pragma unroll
        for (int i = 0; i < 4; ++i) {
            dh_[i] = *(const uint4*)&srcH[i * 4];
            dl_[i] = *(const uint4*)&srcL[i * 4];
        }
    }
}

extern "C" void kernel_launch(void* const* d_in, const int* in_sizes, int n_in,
                              void* d_out, int out_size, void* d_ws, size_t ws_size,
                              hipStream_t stream) {
    const float* x      = (const float*)d_in[0];
    const float* w1     = (const float*)d_in[1];
    const float* w2     = (const float*)d_in[2];
    const float* w3     = (const float*)d_in[3];
    const float* factor = (const float*)d_in[4];
    const float* wf     = (const float*)d_in[5];
    float* out = (float*)d_out;

    const size_t SW = (size_t)(C3 + CC) * CC * 2 * sizeof(ushort);   // w splits (hi+lo)
    int BH = 256;                       // full image per batch if ws allows (~305 MB)
    while (BH > 32) {
        size_t SA_ = (size_t)C3 * (BH + 4) * WW * 4;
        size_t SB_ = (size_t)C3 * BH * WW * 4;
        if (SA_ + SB_ + SW <= ws_size) break;
        BH >>= 1;
    }
    const size_t SA = (size_t)C3 * (BH + 4) * WW * 4;
    const size_t SB = (size_t)C3 * BH * WW * 4;

    float*  A   = (float*)d_ws;                            // qkv1 region; later O hi/lo
    float*  Bq  = (float*)((char*)d_ws + SA);              // qkv3 region; earlier Xt hi/lo
    ushort* Wsp = (ushort*)((char*)d_ws + SA + SB);        // weight splits
    ushort* Whi = Wsp;                                     // [768][192]
    ushort* Wlo = Wsp + (size_t)(C3 + CC) * CC;

    ushort* Xhi = (ushort*)Bq;                             // [(BH+4)*256][192]
    ushort* Xlo = Xhi + (size_t)(BH + 4) * WW * CC;
    ushort* Ohi = (ushort*)A;                              // [6][BH*256][32]
    ushort* Olo = Ohi + (size_t)NHD * BH * WW * DH;

    prep_w<<<dim3((C3 + CC) * CC / 256), dim3(256), 0, stream>>>(w1, wf, Whi, Wlo);

    for (int n = 0; n < NB; ++n) {
        for (int h0 = 0; h0 < HH; h0 += BH) {
            const int strips = BH / 32;
            prep_xt<<<dim3((BH + 4) * (WW / 64)), dim3(256), 0, stream>>>(x, Xhi, Xlo, n, h0, BH);
            gemm_split<<<dim3(((BH + 4) * WW / 128) * (C3 / 64)), dim3(256), 0, stream>>>(
                Whi, Wlo, Xhi, Xlo, A, (BH + 4) * WW, CC, DH, C3 / 64);
            k2_dwdw<<<dim3(C3 * strips / 4), dim3(256), 0, stream>>>(A, w2, w3, Bq, h0, BH, strips);
            k3_attn_mfma<<<dim3(NHD * BH), dim3(512), 0, stream>>>(Bq, factor, Ohi, Olo, BH);
            gemm_split<<<dim3((BH * WW / 128) * (CC / 64)), dim3(256), 0, stream>>>(
                Whi + (size_t)C3 * CC, Wlo + (size_t)C3 * CC, Ohi, Olo,
                out + ((size_t)n * CC) * HH * WW + (size_t)h0 * WW, HH * WW,
                DH, BH * WW * DH, CC / 64);
        }
    }
}